// Round 17
// baseline (261.775 us; speedup 1.0000x reference)
//
#include <hip/hip_runtime.h>
#include <hip/hip_bf16.h>

#define Bc 2
#define Tc 2048
#define Dc 1024
#define Hc 16
#define Mc (Bc*Tc)   // 4096
#define QB 64
#define KB 64
#define NALL 4480    // 3072 qkv | 1024 geo | 4x64 lines | 16 gate | 112 pad

typedef __attribute__((ext_vector_type(8))) short bf16x8;
typedef __attribute__((ext_vector_type(4))) short bf16x4;
typedef __attribute__((ext_vector_type(4))) float fx4;

__device__ __forceinline__ short f2bf(float f) {
  __hip_bfloat16 h = __float2bfloat16(f);
  return *reinterpret_cast<short*>(&h);
}
__device__ __forceinline__ float bf2f(short s) {
  unsigned int u = ((unsigned int)(unsigned short)s) << 16;
  float f;
  __builtin_memcpy(&f, &u, 4);
  return f;
}
// pack two positive f32 -> (bf16(a) | bf16(b)<<16), round-half-up
__device__ __forceinline__ int pk2bf(float a, float b) {
  unsigned int ua, ub;
  __builtin_memcpy(&ua, &a, 4);
  __builtin_memcpy(&ub, &b, 4);
  return (int)(((ua + 0x8000u) >> 16) | (((ub + 0x8000u) >> 16) << 16));
}

#define MFMA(a, b, c) __builtin_amdgcn_mfma_f32_16x16x32_bf16((a), (b), (c), 0, 0, 0)

// async global->LDS, 16B per lane; LDS dest = wave-uniform base + lane*16
#define GLD16(G, L) __builtin_amdgcn_global_load_lds( \
    (const __attribute__((address_space(1))) unsigned int*)(G), \
    (__attribute__((address_space(3))) unsigned int*)(L), 16, 0, 0)

// ---------------------------------------------------------------------------
// fused prologue (r15-proven): f2b | tconv_all | tconv(outw) | biasall
// ---------------------------------------------------------------------------
__global__ __launch_bounds__(256) void prep_k(
    const float* __restrict__ x,
    const float* __restrict__ qkv_w, const float* __restrict__ geow,
    const float* __restrict__ w1w, const float* __restrict__ w2w,
    const float* __restrict__ w1r, const float* __restrict__ w2r,
    const float* __restrict__ gatew, const float* __restrict__ outw,
    const float* __restrict__ qkv_b, const float* __restrict__ geob,
    const float* __restrict__ gateb,
    short* __restrict__ xb, short* __restrict__ wtall,
    short* __restrict__ wtout, float* __restrict__ ball)
{
  __shared__ float tile[32][33];
  const int blk = blockIdx.x;

  if (blk < 4096) {
    const int i = blk * 256 + threadIdx.x;
    const float4 v = ((const float4*)x)[i];
    bf16x4 o;
    o[0] = f2bf(v.x); o[1] = f2bf(v.y); o[2] = f2bf(v.z); o[3] = f2bf(v.w);
    ((bf16x4*)xb)[i] = o;
    return;
  }
  if (blk < 8576) {
    const int b2 = blk - 4096;
    const int n0 = (b2 % 140) * 32, k0 = (b2 / 140) * 32;
    const int tx = threadIdx.x & 31, ty = threadIdx.x >> 5;
    const int n = n0 + tx;
    const float* src = nullptr; int ln = 0, sN = 0;
    if (n < 3072)      { src = qkv_w; ln = n;        sN = 3072; }
    else if (n < 4096) { src = geow;  ln = n - 3072; sN = 1024; }
    else if (n < 4160) { src = w1w;   ln = n - 4096; sN = 64; }
    else if (n < 4224) { src = w2w;   ln = n - 4160; sN = 64; }
    else if (n < 4288) { src = w1r;   ln = n - 4224; sN = 64; }
    else if (n < 4352) { src = w2r;   ln = n - 4288; sN = 64; }
    else if (n < 4368) { src = gatew; ln = n - 4352; sN = 16; }
    #pragma unroll
    for (int i = 0; i < 4; i++)
      tile[ty * 4 + i][tx] = src ? src[(size_t)(k0 + ty * 4 + i) * sN + ln] : 0.f;
    __syncthreads();
    #pragma unroll
    for (int i = 0; i < 4; i++) {
      const int nn = n0 + ty * 4 + i;
      const float s = (nn < 1024) ? 0.125f : 1.f;
      wtall[(size_t)nn * 1024 + k0 + tx] = f2bf(tile[tx][ty * 4 + i] * s);
    }
    return;
  }
  if (blk < 9600) {
    const int b3 = blk - 8576;
    const int n0 = (b3 & 31) * 32, k0 = (b3 >> 5) * 32;
    const int tx = threadIdx.x & 31, ty = threadIdx.x >> 5;
    #pragma unroll
    for (int i = 0; i < 4; i++)
      tile[ty * 4 + i][tx] = outw[(size_t)(k0 + ty * 4 + i) * 1024 + n0 + tx];
    __syncthreads();
    #pragma unroll
    for (int i = 0; i < 4; i++)
      wtout[(size_t)(n0 + ty * 4 + i) * 1024 + k0 + tx] = f2bf(tile[tx][ty * 4 + i]);
    return;
  }
  {
    const int n = (blk - 9600) * 256 + threadIdx.x;
    if (n >= NALL) return;
    float v = 0.f;
    if (n < 1024)      v = qkv_b[n] * 0.125f;
    else if (n < 3072) v = qkv_b[n];
    else if (n < 4096) v = geob[n - 3072];
    else if (n >= 4352 && n < 4368) v = gateb[n - 4352];
    ball[n] = v;
  }
}

// ---------------------------------------------------------------------------
// m97-style bf16 MFMA GEMM: 128x128 tile, XCD-clustered (r16-proven)
// ---------------------------------------------------------------------------
template<bool BF16_OUT>
__global__ __launch_bounds__(256) void gemm_mfma_k(
    const short* __restrict__ A, const short* __restrict__ Bt,
    const float* __restrict__ bias, void* __restrict__ Cv,
    int M, int N, int K)
{
  __shared__ short As[128][32];
  __shared__ short Bs[128][32];
  const int orig = blockIdx.x + blockIdx.y * gridDim.x;
  const int q8 = (gridDim.x * gridDim.y) >> 3;
  const int idx = (orig & 7) * q8 + (orig >> 3);
  const int m0 = (idx / gridDim.x) * 128, n0 = (idx % gridDim.x) * 128;
  const int tid = threadIdx.x;
  const int wave = tid >> 6, lane = tid & 63;
  const int l15 = lane & 15, lg = lane >> 4;
  const int wm = wave >> 1, wn = wave & 1;
  const int srow = lane >> 2;
  const int schk = (lane & 3) * 8;

  const size_t aBase = (size_t)(m0 + wave * 16 + srow) * K + schk;
  const size_t bBase = (size_t)(n0 + wave * 16 + srow) * K + schk;

  fx4 acc[4][4] = {};

  for (int k0 = 0; k0 < K; k0 += 32) {
    __syncthreads();
    GLD16(&A[aBase + k0],              &As[wave * 16][0]);
    GLD16(&A[aBase + (size_t)64 * K + k0], &As[64 + wave * 16][0]);
    GLD16(&Bt[bBase + k0],             &Bs[wave * 16][0]);
    GLD16(&Bt[bBase + (size_t)64 * K + k0], &Bs[64 + wave * 16][0]);
    __syncthreads();
    bf16x8 af[4], bf[4];
    #pragma unroll
    for (int i = 0; i < 4; i++) {
      af[i] = *(const bf16x8*)&As[wm * 64 + i * 16 + l15][8 * lg];
      bf[i] = *(const bf16x8*)&Bs[wn * 64 + i * 16 + l15][8 * lg];
    }
    #pragma unroll
    for (int i = 0; i < 4; i++)
      #pragma unroll
      for (int j = 0; j < 4; j++)
        acc[i][j] = MFMA(af[i], bf[j], acc[i][j]);
  }

  #pragma unroll
  for (int i = 0; i < 4; i++)
    #pragma unroll
    for (int j = 0; j < 4; j++) {
      const int n = n0 + wn * 64 + j * 16 + l15;
      const float bv = bias ? bias[n] : 0.f;
      #pragma unroll
      for (int rg = 0; rg < 4; rg++) {
        const int m = m0 + wm * 64 + i * 16 + lg * 4 + rg;
        const float v = acc[i][j][rg] + bv;
        if constexpr (BF16_OUT)
          ((short*)Cv)[(size_t)m * N + n] = f2bf(v);
        else
          ((float*)Cv)[(size_t)m * N + n] = v;
      }
    }
}

// ---------------------------------------------------------------------------
// 64x128-tile variant for the out-GEMM (512 blocks = 2/CU), XCD-clustered.
// ---------------------------------------------------------------------------
template<bool BF16_OUT>
__global__ __launch_bounds__(256) void gemm_mfma64_k(
    const short* __restrict__ A, const short* __restrict__ Bt,
    const float* __restrict__ bias, void* __restrict__ Cv,
    int M, int N, int K)
{
  __shared__ short As[64][32];
  __shared__ short Bs[128][32];
  const int orig = blockIdx.x + blockIdx.y * gridDim.x;
  const int q8 = (gridDim.x * gridDim.y) >> 3;
  const int idx = (orig & 7) * q8 + (orig >> 3);
  const int m0 = (idx / gridDim.x) * 64, n0 = (idx % gridDim.x) * 128;
  const int tid = threadIdx.x;
  const int wave = tid >> 6, lane = tid & 63;
  const int l15 = lane & 15, lg = lane >> 4;
  const int srow = lane >> 2;
  const int schk = (lane & 3) * 8;

  const size_t aBase = (size_t)(m0 + wave * 16 + srow) * K + schk;
  const size_t bBase = (size_t)(n0 + wave * 16 + srow) * K + schk;

  fx4 acc[4][2] = {};

  for (int k0 = 0; k0 < K; k0 += 32) {
    __syncthreads();
    GLD16(&A[aBase + k0],                   &As[wave * 16][0]);
    GLD16(&Bt[bBase + k0],                  &Bs[wave * 16][0]);
    GLD16(&Bt[bBase + (size_t)64 * K + k0], &Bs[64 + wave * 16][0]);
    __syncthreads();
    bf16x8 af[4], bf[2];
    #pragma unroll
    for (int i = 0; i < 4; i++)
      af[i] = *(const bf16x8*)&As[i * 16 + l15][8 * lg];
    #pragma unroll
    for (int j = 0; j < 2; j++)
      bf[j] = *(const bf16x8*)&Bs[wave * 32 + j * 16 + l15][8 * lg];
    #pragma unroll
    for (int i = 0; i < 4; i++)
      #pragma unroll
      for (int j = 0; j < 2; j++)
        acc[i][j] = MFMA(af[i], bf[j], acc[i][j]);
  }

  #pragma unroll
  for (int i = 0; i < 4; i++)
    #pragma unroll
    for (int j = 0; j < 2; j++) {
      const int n = n0 + wave * 32 + j * 16 + l15;
      const float bv = bias ? bias[n] : 0.f;
      #pragma unroll
      for (int rg = 0; rg < 4; rg++) {
        const int m = m0 + i * 16 + lg * 4 + rg;
        const float v = acc[i][j][rg] + bv;
        if constexpr (BF16_OUT)
          ((short*)Cv)[(size_t)m * N + n] = f2bf(v);
        else
          ((float*)Cv)[(size_t)m * N + n] = v;
      }
    }
}

// ---------------------------------------------------------------------------
// Pluecker lines (+ gate fused).
// ---------------------------------------------------------------------------
__device__ __forceinline__ void exterior6(const float a[4], const float c[4], float L[6]) {
  L[0] = a[0]*c[1] - a[1]*c[0];
  L[1] = a[0]*c[2] - a[2]*c[0];
  L[2] = a[0]*c[3] - a[3]*c[0];
  L[3] = a[1]*c[2] - a[2]*c[1];
  L[4] = a[1]*c[3] - a[3]*c[1];
  L[5] = a[2]*c[3] - a[3]*c[2];
}

__device__ __forceinline__ void load4bf(const short* p, float o[4]) {
  const bf16x4 v = *(const bf16x4*)p;
  o[0] = bf2f(v[0]); o[1] = bf2f(v[1]); o[2] = bf2f(v[2]); o[3] = bf2f(v[3]);
}

__global__ void lines_k(const short* __restrict__ allb,
                        const float* __restrict__ incs,
                        short* __restrict__ JWb, short* __restrict__ RLb,
                        float* __restrict__ gatev)
{
  const int idx = blockIdx.x * 256 + threadIdx.x;
  if (idx >= Bc * Tc * Hc) return;
  const int h = idx & 15;
  const int t = (idx >> 4) & (Tc - 1);
  const int b = idx >> 15;
  const size_t row = (size_t)b * Tc + t;
  const size_t lrow = ((size_t)(b * Hc + h) * Tc + t) * 8;

  float a[4] = {0.f, 0.f, 0.f, 0.f};
  float c[4];
  load4bf(&allb[row * NALL + 4160 + h * 4], c);
  if (t > 0) load4bf(&allb[(row - 1) * NALL + 4096 + h * 4], a);

  float L[6];
  exterior6(a, c, L);
  float n = sqrtf(L[0]*L[0] + L[1]*L[1] + L[2]*L[2] + L[3]*L[3] + L[4]*L[4] + L[5]*L[5]);
  float inv = 1.f / fmaxf(n, 1e-12f);
  const float s = incs[h];
  bf16x8 jw;
  jw[0] = f2bf( L[5] * inv * s);
  jw[1] = f2bf(-L[4] * inv * s);
  jw[2] = f2bf( L[3] * inv * s);
  jw[3] = f2bf( L[2] * inv * s);
  jw[4] = f2bf(-L[1] * inv * s);
  jw[5] = f2bf( L[0] * inv * s);
  jw[6] = 0; jw[7] = 0;
  *(bf16x8*)&JWb[lrow] = jw;

  load4bf(&allb[row * NALL + 4224 + h * 4], a);
  load4bf(&allb[row * NALL + 4288 + h * 4], c);
  exterior6(a, c, L);
  n = sqrtf(L[0]*L[0] + L[1]*L[1] + L[2]*L[2] + L[3]*L[3] + L[4]*L[4] + L[5]*L[5]);
  inv = 1.f / fmaxf(n, 1e-12f);
  bf16x8 rl;
  #pragma unroll
  for (int i = 0; i < 6; i++) rl[i] = f2bf(L[i] * inv);
  rl[6] = 0; rl[7] = 0;
  *(bf16x8*)&RLb[lrow] = rl;

  if (h == 0) {
    float ssum = 0.f;
    #pragma unroll
    for (int hh = 0; hh < 16; hh++) {
      const float v = bf2f(allb[row * NALL + 4352 + hh]);
      ssum += 1.f / (1.f + __expf(-v));
    }
    gatev[row] = ssum * (1.f / 16.f);
  }
}

// ---------------------------------------------------------------------------
// Dual flash attention v8: champion math widened to KB=64 k-tiles — halves
// the barrier count (2 barriers per 128 k-rows). Per 64-tile: 4 col-groups;
// P slots in two 32-halves, each with the proven perm k(s)=16(s&1)+(s>>1);
// V/G staged to permuted+chunk-XOR columns per 32-half. Pairing keeps 33
// uniform 64-tiles/block.
// ---------------------------------------------------------------------------
#define LOADK64(K0, kf, jw) { \
  _Pragma("unroll") for (int cg = 0; cg < 4; cg++) { \
    const size_t rb = (size_t)(b * Tc + (K0) + cg * 16 + l15) * NALL + 1024 + h * 64; \
    kf[cg][0] = *(const bf16x8*)&allb[rb + lg * 8]; \
    kf[cg][1] = *(const bf16x8*)&allb[rb + 32 + lg * 8]; \
    jw[cg] = z8; \
    if (lg == 0) jw[cg] = *(const bf16x8*)&JWb[(size_t)(bh * Tc + (K0) + cg * 16 + l15) * 8]; \
  } }

#define LOADVG64(K0, v0, v1, g0, g1) { \
  const size_t r0 = (size_t)(b * Tc + (K0) + kk) * NALL + h * 64 + dg; \
  const size_t r1 = (size_t)(b * Tc + (K0) + kk + 32) * NALL + h * 64 + dg; \
  v0 = *(const bf16x8*)&allb[r0 + 2048]; \
  g0 = *(const bf16x8*)&allb[r0 + 3072]; \
  v1 = *(const bf16x8*)&allb[r1 + 2048]; \
  g1 = *(const bf16x8*)&allb[r1 + 3072]; }

#define STAGEVG64(CUR, v0, v1, g0, g1) { \
  _Pragma("unroll") for (int j = 0; j < 8; j++) { \
    const int d = dg + j; \
    Vt[CUR][d][pcol]      = v0[j]; Gt[CUR][d][pcol]      = g0[j]; \
    Vt[CUR][d][32 + pcol] = v1[j]; Gt[CUR][d][32 + pcol] = g1[j]; \
  } }

#define COMPUTE64(K0, CUR, kf, jw) \
  if ((K0) <= qhi) { \
    fx4 z = {0.f, 0.f, 0.f, 0.f}; \
    fx4 sS[4], sG[4]; \
    __builtin_amdgcn_s_setprio(1); \
    _Pragma("unroll") for (int cg = 0; cg < 4; cg++) { \
      sS[cg] = MFMA(qf0, kf[cg][0], z); \
      sS[cg] = MFMA(qf1, kf[cg][1], sS[cg]); \
      sG[cg] = MFMA(rlf, jw[cg], z); \
    } \
    __builtin_amdgcn_s_setprio(0); \
    if ((K0) + KB - 1 > q0 + wave * 16) { \
      _Pragma("unroll") for (int cg = 0; cg < 4; cg++) { \
        const int kg = (K0) + cg * 16 + l15; \
        _Pragma("unroll") for (int r = 0; r < 4; r++) { \
          const int qg = q0 + wave * 16 + lg * 4 + r; \
          if (kg > qg) { sS[cg][r] = -1e30f; sG[cg][r] = -1e30f; } \
        } } } \
    _Pragma("unroll") for (int r = 0; r < 4; r++) { \
      const int ql = lg * 4 + r; \
      const float p0 = __expf(sS[0][r]); const float p1 = __expf(sS[1][r]); \
      const float p2 = __expf(sS[2][r]); const float p3 = __expf(sS[3][r]); \
      lpS[r] += (p0 + p1) + (p2 + p3); \
      *(int*)&Ps[wave][ql][2 * l15]      = pk2bf(p0, p1); \
      *(int*)&Ps[wave][ql][32 + 2 * l15] = pk2bf(p2, p3); \
      const float g0 = __expf(sG[0][r]); const float g1 = __expf(sG[1][r]); \
      const float g2 = __expf(sG[2][r]); const float g3 = __expf(sG[3][r]); \
      lpG[r] += (g0 + g1) + (g2 + g3); \
      *(int*)&Pg[wave][ql][2 * l15]      = pk2bf(g0, g1); \
      *(int*)&Pg[wave][ql][32 + 2 * l15] = pk2bf(g2, g3); \
    } \
    const bf16x8 paL  = *(const bf16x8*)&Ps[wave][l15][8 * lg]; \
    const bf16x8 paH  = *(const bf16x8*)&Ps[wave][l15][32 + 8 * lg]; \
    const bf16x8 pgaL = *(const bf16x8*)&Pg[wave][l15][8 * lg]; \
    const bf16x8 pgaH = *(const bf16x8*)&Pg[wave][l15][32 + 8 * lg]; \
    __builtin_amdgcn_s_setprio(1); \
    _Pragma("unroll") for (int dt = 0; dt < 4; dt++) { \
      const int dV = dt * 16 + l15; \
      const int sw = 8 * (lg ^ ((dV >> 3) & 3)); \
      accS[dt] = MFMA(paL, *(const bf16x8*)&Vt[CUR][dV][sw],      accS[dt]); \
      accS[dt] = MFMA(paH, *(const bf16x8*)&Vt[CUR][dV][32 + sw], accS[dt]); \
      accG[dt] = MFMA(pgaL, *(const bf16x8*)&Gt[CUR][dV][sw],      accG[dt]); \
      accG[dt] = MFMA(pgaH, *(const bf16x8*)&Gt[CUR][dV][32 + sw], accG[dt]); \
    } \
    __builtin_amdgcn_s_setprio(0); \
  }

__global__ __launch_bounds__(256) void attn3_k(
    const short* __restrict__ allb,  // (4096, 4480) bf16: q|k|v|geo|lines|gate
    const short* __restrict__ RLb,   // (B*H, T, 8) bf16
    const short* __restrict__ JWb,   // (B*H, T, 8) bf16, inc_scale folded
    const float* __restrict__ gate,  // (4096)
    short* __restrict__ combb)       // (4096, 1024) bf16
{
  const int orig = blockIdx.x;        // 0..511
  const int xcd  = orig & 7;
  const int idx  = orig >> 3;         // 0..63
  const int pairIdx = idx & 15;
  const int bh   = xcd + 8 * (idx >> 4);  // 4 bh per XCD
  const int b = bh >> 4, h = bh & 15;
  const int tid = threadIdx.x;
  const int wave = tid >> 6;
  const int lane = tid & 63;
  const int l15 = lane & 15;
  const int lg  = lane >> 4;
  const int kk  = tid >> 3;           // staging k row 0..31 (and +32)
  const int dg  = (tid & 7) * 8;      // staging d group
  // permuted slot of k row kk within its 32-half, then chunk-XOR bank swizzle
  const int ps_ = 2 * (kk & 15) + (kk >> 4);
  const int pcol = (((ps_ >> 3) ^ ((dg >> 3) & 3)) << 3) | (ps_ & 7);

  __shared__ short Vt[2][64][72];
  __shared__ short Gt[2][64][72];
  __shared__ short Ps[4][16][72];
  __shared__ short Pg[4][16][72];

  const bf16x8 z8 = {0, 0, 0, 0, 0, 0, 0, 0};

  for (int half = 0; half < 2; half++) {
    const int qt = half ? (31 - pairIdx) : pairIdx;
    const int q0 = qt * QB;
    const int nkt = qt + 1;           // 64-wide k-tiles
    const int qrow = wave * 16 + l15;
    const int qhi = q0 + wave * 16 + 15;

    const size_t qrb = (size_t)(b * Tc + q0 + qrow) * NALL + h * 64;
    const bf16x8 qf0 = *(const bf16x8*)&allb[qrb + lg * 8];
    const bf16x8 qf1 = *(const bf16x8*)&allb[qrb + 32 + lg * 8];
    bf16x8 rlf = z8;
    if (lg == 0) rlf = *(const bf16x8*)&RLb[(size_t)(bh * Tc + q0 + qrow) * 8];

    fx4 accS[4] = {}, accG[4] = {};
    float lpS[4] = {0.f, 0.f, 0.f, 0.f};
    float lpG[4] = {0.f, 0.f, 0.f, 0.f};

    bf16x8 kfA[4][2], jwA[4], kfB[4][2], jwB[4];
    bf16x8 vA0, vA1, gA0, gA1, vB0, vB1, gB0, gB1;

    // prologue: tile 0 operands into set A (registers only)
    LOADK64(0, kfA, jwA);
    LOADVG64(0, vA0, vA1, gA0, gA1);

    __syncthreads();   // prev half's readers done before overwriting buf0

    for (int kt = 0; kt < nkt; kt += 2) {
      STAGEVG64(0, vA0, vA1, gA0, gA1);
      if (kt + 1 < nkt) {
        LOADK64((kt + 1) * KB, kfB, jwB);
        LOADVG64((kt + 1) * KB, vB0, vB1, gB0, gB1);
      }
      __syncthreads();          // buf0 ready
      COMPUTE64(kt * KB, 0, kfA, jwA);
      if (kt + 1 >= nkt) break;
      STAGEVG64(1, vB0, vB1, gB0, gB1);
      if (kt + 2 < nkt) {
        LOADK64((kt + 2) * KB, kfA, jwA);
        LOADVG64((kt + 2) * KB, vA0, vA1, gA0, gA1);
      }
      __syncthreads();          // buf1 ready; all waves done with buf0
      COMPUTE64((kt + 1) * KB, 1, kfB, jwB);
    }
    __syncthreads();            // all waves done before next half re-stages

    // epilogue
    #pragma unroll
    for (int r = 0; r < 4; r++) {
      float ls = lpS[r];
      ls += __shfl_xor(ls, 1); ls += __shfl_xor(ls, 2);
      ls += __shfl_xor(ls, 4); ls += __shfl_xor(ls, 8);
      float lgeo = lpG[r];
      lgeo += __shfl_xor(lgeo, 1); lgeo += __shfl_xor(lgeo, 2);
      lgeo += __shfl_xor(lgeo, 4); lgeo += __shfl_xor(lgeo, 8);
      const int qg = q0 + wave * 16 + lg * 4 + r;
      const float gt = gate[(size_t)b * Tc + qg];
      const float invS = (1.f - gt) / ls;
      const float invG = gt / lgeo;
      #pragma unroll
      for (int dt = 0; dt < 4; dt++) {
        const float o = accS[dt][r] * invS + accG[dt][r] * invG;
        combb[(size_t)(b * Tc + qg) * 1024 + h * 64 + dt * 16 + l15] = f2bf(o);
      }
    }
  }
}

// ---------------------------------------------------------------------------
extern "C" void kernel_launch(void* const* d_in, const int* in_sizes, int n_in,
                              void* d_out, int out_size, void* d_ws, size_t ws_size,
                              hipStream_t stream) {
  (void)in_sizes; (void)n_in; (void)out_size; (void)ws_size;
  const float* x     = (const float*)d_in[0];
  const float* qkv_w = (const float*)d_in[1];
  const float* qkv_b = (const float*)d_in[2];
  const float* w1w   = (const float*)d_in[3];
  const float* w2w   = (const float*)d_in[4];
  const float* w1r   = (const float*)d_in[5];
  const float* w2r   = (const float*)d_in[6];
  const float* geow  = (const float*)d_in[7];
  const float* geob  = (const float*)d_in[8];
  const float* gatew = (const float*)d_in[9];
  const float* gateb = (const float*)d_in[10];
  const float* incs  = (const float*)d_in[11];
  const float* outw  = (const float*)d_in[12];
  const float* outb  = (const float*)d_in[13];
  float* out = (float*)d_out;

  char* p = (char*)d_ws;
  short* xb    = (short*)p;  p += (size_t)4096 * 1024 * 2;   // 8 MB
  short* wtall = (short*)p;  p += (size_t)NALL * 1024 * 2;   // 9.2 MB
  short* allb  = (short*)p;  p += (size_t)4096 * NALL * 2;   // 36.7 MB
  short* combb = (short*)p;  p += (size_t)4096 * 1024 * 2;   // 8 MB
  short* wtout = (short*)p;  p += (size_t)1024 * 1024 * 2;   // 2 MB
  short* JWb   = (short*)p;  p += (size_t)32 * 2048 * 8 * 2; // 1 MB
  short* RLb   = (short*)p;  p += (size_t)32 * 2048 * 8 * 2; // 1 MB
  float* ball  = (float*)p;  p += (size_t)NALL * 4;
  float* gatev = (float*)p;  p += (size_t)4096 * 4;

  const dim3 blk(256);

  // fused prologue: f2b | tconv_all | tconv(outw) | biasall
  prep_k<<<dim3(9618), blk, 0, stream>>>(x, qkv_w, geow, w1w, w2w, w1r, w2r,
                                         gatew, outw, qkv_b, geob, gateb,
                                         xb, wtall, wtout, ball);

  // merged projection GEMM: (4096 x 1024) @ (1024 x 4480) -> allb
  gemm_mfma_k<true><<<dim3(NALL / 128, 32), blk, 0, stream>>>(xb, wtall, ball, allb, 4096, NALL, 1024);

  lines_k<<<dim3((Bc * Tc * Hc + 255) / 256), blk, 0, stream>>>(allb, incs, JWb, RLb, gatev);

  attn3_k<<<dim3(512), blk, 0, stream>>>(allb, RLb, JWb, gatev, combb);

  // final projection -> fp32 output (64x128 tiles: 512 blocks = 2/CU)
  gemm_mfma64_k<false><<<dim3(8, 64), blk, 0, stream>>>(combb, wtout, outb, (void*)out, 4096, 1024, 1024);
}

// Round 18
// 190.899 us; speedup vs baseline: 1.3713x; 1.3713x over previous
//
#include <hip/hip_runtime.h>
#include <hip/hip_bf16.h>

#define Bc 2
#define Tc 2048
#define Dc 1024
#define Hc 16
#define Mc (Bc*Tc)   // 4096
#define QB 64
#define KB 32
#define NALL 4480    // 3072 qkv | 1024 geo | 4x64 lines | 16 gate | 112 pad

typedef __attribute__((ext_vector_type(8))) short bf16x8;
typedef __attribute__((ext_vector_type(4))) short bf16x4;
typedef __attribute__((ext_vector_type(4))) float fx4;

__device__ __forceinline__ short f2bf(float f) {
  __hip_bfloat16 h = __float2bfloat16(f);
  return *reinterpret_cast<short*>(&h);
}
__device__ __forceinline__ float bf2f(short s) {
  unsigned int u = ((unsigned int)(unsigned short)s) << 16;
  float f;
  __builtin_memcpy(&f, &u, 4);
  return f;
}
// pack two positive f32 -> (bf16(a) | bf16(b)<<16), round-half-up
__device__ __forceinline__ int pk2bf(float a, float b) {
  unsigned int ua, ub;
  __builtin_memcpy(&ua, &a, 4);
  __builtin_memcpy(&ub, &b, 4);
  return (int)(((ua + 0x8000u) >> 16) | (((ub + 0x8000u) >> 16) << 16));
}

#define MFMA(a, b, c) __builtin_amdgcn_mfma_f32_16x16x32_bf16((a), (b), (c), 0, 0, 0)

// async global->LDS, 16B per lane; LDS dest = wave-uniform base + lane*16
#define GLD16(G, L) __builtin_amdgcn_global_load_lds( \
    (const __attribute__((address_space(1))) unsigned int*)(G), \
    (__attribute__((address_space(3))) unsigned int*)(L), 16, 0, 0)

// ---------------------------------------------------------------------------
// fused prologue: blockIdx ranges ->
//   [0,4096)   : x fp32 -> bf16        [4096,8576) : merged weight T+convert
//   [8576,9600): outw T+convert        [9600,9618) : fused bias vector
// ---------------------------------------------------------------------------
__global__ __launch_bounds__(256) void prep_k(
    const float* __restrict__ x,
    const float* __restrict__ qkv_w, const float* __restrict__ geow,
    const float* __restrict__ w1w, const float* __restrict__ w2w,
    const float* __restrict__ w1r, const float* __restrict__ w2r,
    const float* __restrict__ gatew, const float* __restrict__ outw,
    const float* __restrict__ qkv_b, const float* __restrict__ geob,
    const float* __restrict__ gateb,
    short* __restrict__ xb, short* __restrict__ wtall,
    short* __restrict__ wtout, float* __restrict__ ball)
{
  __shared__ float tile[32][33];
  const int blk = blockIdx.x;

  if (blk < 4096) {                      // ---- f2b on x ----
    const int i = blk * 256 + threadIdx.x;
    const float4 v = ((const float4*)x)[i];
    bf16x4 o;
    o[0] = f2bf(v.x); o[1] = f2bf(v.y); o[2] = f2bf(v.z); o[3] = f2bf(v.w);
    ((bf16x4*)xb)[i] = o;
    return;
  }
  if (blk < 8576) {                      // ---- tconv_all ----
    const int b2 = blk - 4096;           // 0..4479 -> (n0, k0)
    const int n0 = (b2 % 140) * 32, k0 = (b2 / 140) * 32;
    const int tx = threadIdx.x & 31, ty = threadIdx.x >> 5;
    const int n = n0 + tx;
    const float* src = nullptr; int ln = 0, sN = 0;
    if (n < 3072)      { src = qkv_w; ln = n;        sN = 3072; }
    else if (n < 4096) { src = geow;  ln = n - 3072; sN = 1024; }
    else if (n < 4160) { src = w1w;   ln = n - 4096; sN = 64; }
    else if (n < 4224) { src = w2w;   ln = n - 4160; sN = 64; }
    else if (n < 4288) { src = w1r;   ln = n - 4224; sN = 64; }
    else if (n < 4352) { src = w2r;   ln = n - 4288; sN = 64; }
    else if (n < 4368) { src = gatew; ln = n - 4352; sN = 16; }
    #pragma unroll
    for (int i = 0; i < 4; i++)
      tile[ty * 4 + i][tx] = src ? src[(size_t)(k0 + ty * 4 + i) * sN + ln] : 0.f;
    __syncthreads();
    #pragma unroll
    for (int i = 0; i < 4; i++) {
      const int nn = n0 + ty * 4 + i;
      const float s = (nn < 1024) ? 0.125f : 1.f;
      wtall[(size_t)nn * 1024 + k0 + tx] = f2bf(tile[tx][ty * 4 + i] * s);
    }
    return;
  }
  if (blk < 9600) {                      // ---- tconv outw ----
    const int b3 = blk - 8576;           // 0..1023
    const int n0 = (b3 & 31) * 32, k0 = (b3 >> 5) * 32;
    const int tx = threadIdx.x & 31, ty = threadIdx.x >> 5;
    #pragma unroll
    for (int i = 0; i < 4; i++)
      tile[ty * 4 + i][tx] = outw[(size_t)(k0 + ty * 4 + i) * 1024 + n0 + tx];
    __syncthreads();
    #pragma unroll
    for (int i = 0; i < 4; i++)
      wtout[(size_t)(n0 + ty * 4 + i) * 1024 + k0 + tx] = f2bf(tile[tx][ty * 4 + i]);
    return;
  }
  {                                      // ---- biasall ----
    const int n = (blk - 9600) * 256 + threadIdx.x;
    if (n >= NALL) return;
    float v = 0.f;
    if (n < 1024)      v = qkv_b[n] * 0.125f;
    else if (n < 3072) v = qkv_b[n];
    else if (n < 4096) v = geob[n - 3072];
    else if (n >= 4352 && n < 4368) v = gateb[n - 4352];
    ball[n] = v;
  }
}

// ---------------------------------------------------------------------------
// m97-style bf16 MFMA GEMM: 128x128 tile, XCD-clustered block mapping.
// ---------------------------------------------------------------------------
template<bool BF16_OUT>
__global__ __launch_bounds__(256) void gemm_mfma_k(
    const short* __restrict__ A, const short* __restrict__ Bt,
    const float* __restrict__ bias, void* __restrict__ Cv,
    int M, int N, int K)
{
  __shared__ short As[128][32];
  __shared__ short Bs[128][32];
  // bijective XCD swizzle (nwg % 8 == 0): each XCD gets contiguous m-stripes
  const int orig = blockIdx.x + blockIdx.y * gridDim.x;
  const int q8 = (gridDim.x * gridDim.y) >> 3;
  const int idx = (orig & 7) * q8 + (orig >> 3);
  const int m0 = (idx / gridDim.x) * 128, n0 = (idx % gridDim.x) * 128;
  const int tid = threadIdx.x;
  const int wave = tid >> 6, lane = tid & 63;
  const int l15 = lane & 15, lg = lane >> 4;
  const int wm = wave >> 1, wn = wave & 1;
  const int srow = lane >> 2;
  const int schk = (lane & 3) * 8;

  const size_t aBase = (size_t)(m0 + wave * 16 + srow) * K + schk;
  const size_t bBase = (size_t)(n0 + wave * 16 + srow) * K + schk;

  fx4 acc[4][4] = {};

  for (int k0 = 0; k0 < K; k0 += 32) {
    __syncthreads();
    GLD16(&A[aBase + k0],              &As[wave * 16][0]);
    GLD16(&A[aBase + (size_t)64 * K + k0], &As[64 + wave * 16][0]);
    GLD16(&Bt[bBase + k0],             &Bs[wave * 16][0]);
    GLD16(&Bt[bBase + (size_t)64 * K + k0], &Bs[64 + wave * 16][0]);
    __syncthreads();
    bf16x8 af[4], bf[4];
    #pragma unroll
    for (int i = 0; i < 4; i++) {
      af[i] = *(const bf16x8*)&As[wm * 64 + i * 16 + l15][8 * lg];
      bf[i] = *(const bf16x8*)&Bs[wn * 64 + i * 16 + l15][8 * lg];
    }
    #pragma unroll
    for (int i = 0; i < 4; i++)
      #pragma unroll
      for (int j = 0; j < 4; j++)
        acc[i][j] = MFMA(af[i], bf[j], acc[i][j]);
  }

  #pragma unroll
  for (int i = 0; i < 4; i++)
    #pragma unroll
    for (int j = 0; j < 4; j++) {
      const int n = n0 + wn * 64 + j * 16 + l15;
      const float bv = bias ? bias[n] : 0.f;
      #pragma unroll
      for (int rg = 0; rg < 4; rg++) {
        const int m = m0 + wm * 64 + i * 16 + lg * 4 + rg;
        const float v = acc[i][j][rg] + bv;
        if constexpr (BF16_OUT)
          ((short*)Cv)[(size_t)m * N + n] = f2bf(v);
        else
          ((float*)Cv)[(size_t)m * N + n] = v;
      }
    }
}

// ---------------------------------------------------------------------------
// 64x128-tile variant for the out-GEMM (512 blocks = 2/CU), XCD-clustered.
// ---------------------------------------------------------------------------
template<bool BF16_OUT>
__global__ __launch_bounds__(256) void gemm_mfma64_k(
    const short* __restrict__ A, const short* __restrict__ Bt,
    const float* __restrict__ bias, void* __restrict__ Cv,
    int M, int N, int K)
{
  __shared__ short As[64][32];
  __shared__ short Bs[128][32];
  const int orig = blockIdx.x + blockIdx.y * gridDim.x;
  const int q8 = (gridDim.x * gridDim.y) >> 3;
  const int idx = (orig & 7) * q8 + (orig >> 3);
  const int m0 = (idx / gridDim.x) * 64, n0 = (idx % gridDim.x) * 128;
  const int tid = threadIdx.x;
  const int wave = tid >> 6, lane = tid & 63;
  const int l15 = lane & 15, lg = lane >> 4;
  const int srow = lane >> 2;
  const int schk = (lane & 3) * 8;

  const size_t aBase = (size_t)(m0 + wave * 16 + srow) * K + schk;
  const size_t bBase = (size_t)(n0 + wave * 16 + srow) * K + schk;

  fx4 acc[4][2] = {};

  for (int k0 = 0; k0 < K; k0 += 32) {
    __syncthreads();
    GLD16(&A[aBase + k0],                   &As[wave * 16][0]);
    GLD16(&Bt[bBase + k0],                  &Bs[wave * 16][0]);
    GLD16(&Bt[bBase + (size_t)64 * K + k0], &Bs[64 + wave * 16][0]);
    __syncthreads();
    bf16x8 af[4], bf[2];
    #pragma unroll
    for (int i = 0; i < 4; i++)
      af[i] = *(const bf16x8*)&As[i * 16 + l15][8 * lg];
    #pragma unroll
    for (int j = 0; j < 2; j++)
      bf[j] = *(const bf16x8*)&Bs[wave * 32 + j * 16 + l15][8 * lg];
    #pragma unroll
    for (int i = 0; i < 4; i++)
      #pragma unroll
      for (int j = 0; j < 2; j++)
        acc[i][j] = MFMA(af[i], bf[j], acc[i][j]);
  }

  #pragma unroll
  for (int i = 0; i < 4; i++)
    #pragma unroll
    for (int j = 0; j < 2; j++) {
      const int n = n0 + wave * 32 + j * 16 + l15;
      const float bv = bias ? bias[n] : 0.f;
      #pragma unroll
      for (int rg = 0; rg < 4; rg++) {
        const int m = m0 + i * 16 + lg * 4 + rg;
        const float v = acc[i][j][rg] + bv;
        if constexpr (BF16_OUT)
          ((short*)Cv)[(size_t)m * N + n] = f2bf(v);
        else
          ((float*)Cv)[(size_t)m * N + n] = v;
      }
    }
}

// ---------------------------------------------------------------------------
// Pluecker lines (+ gate fused).
// ---------------------------------------------------------------------------
__device__ __forceinline__ void exterior6(const float a[4], const float c[4], float L[6]) {
  L[0] = a[0]*c[1] - a[1]*c[0];
  L[1] = a[0]*c[2] - a[2]*c[0];
  L[2] = a[0]*c[3] - a[3]*c[0];
  L[3] = a[1]*c[2] - a[2]*c[1];
  L[4] = a[1]*c[3] - a[3]*c[1];
  L[5] = a[2]*c[3] - a[3]*c[2];
}

__device__ __forceinline__ void load4bf(const short* p, float o[4]) {
  const bf16x4 v = *(const bf16x4*)p;
  o[0] = bf2f(v[0]); o[1] = bf2f(v[1]); o[2] = bf2f(v[2]); o[3] = bf2f(v[3]);
}

__global__ void lines_k(const short* __restrict__ allb,
                        const float* __restrict__ incs,
                        short* __restrict__ JWb, short* __restrict__ RLb,
                        float* __restrict__ gatev)
{
  const int idx = blockIdx.x * 256 + threadIdx.x;
  if (idx >= Bc * Tc * Hc) return;
  const int h = idx & 15;
  const int t = (idx >> 4) & (Tc - 1);
  const int b = idx >> 15;
  const size_t row = (size_t)b * Tc + t;
  const size_t lrow = ((size_t)(b * Hc + h) * Tc + t) * 8;

  float a[4] = {0.f, 0.f, 0.f, 0.f};
  float c[4];
  load4bf(&allb[row * NALL + 4160 + h * 4], c);              // w2(x)
  if (t > 0) load4bf(&allb[(row - 1) * NALL + 4096 + h * 4], a);  // w1(x_prev)

  float L[6];
  exterior6(a, c, L);
  float n = sqrtf(L[0]*L[0] + L[1]*L[1] + L[2]*L[2] + L[3]*L[3] + L[4]*L[4] + L[5]*L[5]);
  float inv = 1.f / fmaxf(n, 1e-12f);
  const float s = incs[h];
  bf16x8 jw;
  jw[0] = f2bf( L[5] * inv * s);
  jw[1] = f2bf(-L[4] * inv * s);
  jw[2] = f2bf( L[3] * inv * s);
  jw[3] = f2bf( L[2] * inv * s);
  jw[4] = f2bf(-L[1] * inv * s);
  jw[5] = f2bf( L[0] * inv * s);
  jw[6] = 0; jw[7] = 0;
  *(bf16x8*)&JWb[lrow] = jw;

  load4bf(&allb[row * NALL + 4224 + h * 4], a);              // r1(x)
  load4bf(&allb[row * NALL + 4288 + h * 4], c);              // r2(x)
  exterior6(a, c, L);
  n = sqrtf(L[0]*L[0] + L[1]*L[1] + L[2]*L[2] + L[3]*L[3] + L[4]*L[4] + L[5]*L[5]);
  inv = 1.f / fmaxf(n, 1e-12f);
  bf16x8 rl;
  #pragma unroll
  for (int i = 0; i < 6; i++) rl[i] = f2bf(L[i] * inv);
  rl[6] = 0; rl[7] = 0;
  *(bf16x8*)&RLb[lrow] = rl;

  if (h == 0) {
    float ssum = 0.f;
    #pragma unroll
    for (int hh = 0; hh < 16; hh++) {
      const float v = bf2f(allb[row * NALL + 4352 + hh]);
      ssum += 1.f / (1.f + __expf(-v));
    }
    gatev[row] = ssum * (1.f / 16.f);
  }
}

// ---------------------------------------------------------------------------
// Dual flash attention v3 — r16 champion: paired q-tiles, XCD clustering,
// double-buffered V/G staging, pair-packed P stores (permuted k-order).
// ---------------------------------------------------------------------------
#define LOADK(K0, a0, a1, b0, b1) { \
  const size_t rb0 = (size_t)(b * Tc + (K0) + l15) * NALL + 1024 + h * 64; \
  const size_t rb1 = rb0 + (size_t)16 * NALL; \
  a0 = *(const bf16x8*)&allb[rb0 + lg * 8]; \
  a1 = *(const bf16x8*)&allb[rb0 + 32 + lg * 8]; \
  b0 = *(const bf16x8*)&allb[rb1 + lg * 8]; \
  b1 = *(const bf16x8*)&allb[rb1 + 32 + lg * 8]; }

#define LOADJW(K0, j0, j1) { \
  j0 = z8; j1 = z8; \
  if (lg == 0) { \
    j0 = *(const bf16x8*)&JWb[(size_t)(bh * Tc + (K0) + l15) * 8]; \
    j1 = *(const bf16x8*)&JWb[(size_t)(bh * Tc + (K0) + 16 + l15) * 8]; \
  } }

#define LOADVG(K0, vr, gr) { \
  vr = *(const bf16x8*)&allb[(size_t)(b * Tc + (K0) + kk) * NALL + 2048 + h * 64 + dg]; \
  gr = *(const bf16x8*)&allb[(size_t)(b * Tc + (K0) + kk) * NALL + 3072 + h * 64 + dg]; }

// stage row k=kk into permuted slot column (thread-constant pcol)
#define STAGEVG(CUR, vr, gr) { \
  _Pragma("unroll") for (int j = 0; j < 8; j++) { \
    const int d = dg + j; \
    Vt[CUR][d][pcol] = vr[j]; Gt[CUR][d][pcol] = gr[j]; \
  } }

#define COMPUTE(K0, CUR, ka0, ka1, kb0, kb1, jw0, jw1) \
  if ((K0) <= qhi) { \
    fx4 z = {0.f, 0.f, 0.f, 0.f}; \
    fx4 sS0, sS1, sG0, sG1; \
    __builtin_amdgcn_s_setprio(1); \
    sS0 = MFMA(qf0, ka0, z); sS0 = MFMA(qf1, ka1, sS0); \
    sS1 = MFMA(qf0, kb0, z); sS1 = MFMA(qf1, kb1, sS1); \
    sG0 = MFMA(rlf, jw0, z); sG1 = MFMA(rlf, jw1, z); \
    __builtin_amdgcn_s_setprio(0); \
    if ((K0) + KB - 1 > q0 + wave * 16) { \
      const int kg0 = (K0) + l15, kg1 = (K0) + 16 + l15; \
      _Pragma("unroll") for (int r = 0; r < 4; r++) { \
        const int qg = q0 + wave * 16 + lg * 4 + r; \
        if (kg0 > qg) { sS0[r] = -1e30f; sG0[r] = -1e30f; } \
        if (kg1 > qg) { sS1[r] = -1e30f; sG1[r] = -1e30f; } \
      } } \
    _Pragma("unroll") for (int r = 0; r < 4; r++) { \
      const int ql = lg * 4 + r; \
      const float p0 = __expf(sS0[r]); const float p1 = __expf(sS1[r]); \
      lpS[r] += p0 + p1; \
      *(int*)&Ps[wave][ql][2 * l15] = pk2bf(p0, p1); \
      const float g0 = __expf(sG0[r]); const float g1 = __expf(sG1[r]); \
      lpG[r] += g0 + g1; \
      *(int*)&Pg[wave][ql][2 * l15] = pk2bf(g0, g1); \
    } \
    const bf16x8 pa  = *(const bf16x8*)&Ps[wave][l15][8 * lg]; \
    const bf16x8 pga = *(const bf16x8*)&Pg[wave][l15][8 * lg]; \
    __builtin_amdgcn_s_setprio(1); \
    _Pragma("unroll") for (int dt = 0; dt < 4; dt++) { \
      const int dV = dt * 16 + l15; \
      const int swz = 8 * (lg ^ ((dV >> 3) & 3)); \
      accS[dt] = MFMA(pa,  *(const bf16x8*)&Vt[CUR][dV][swz], accS[dt]); \
      accG[dt] = MFMA(pga, *(const bf16x8*)&Gt[CUR][dV][swz], accG[dt]); \
    } \
    __builtin_amdgcn_s_setprio(0); \
  }

__global__ __launch_bounds__(256) void attn3_k(
    const short* __restrict__ allb,  // (4096, 4480) bf16: q|k|v|geo|lines|gate
    const short* __restrict__ RLb,   // (B*H, T, 8) bf16
    const short* __restrict__ JWb,   // (B*H, T, 8) bf16, inc_scale folded
    const float* __restrict__ gate,  // (4096)
    short* __restrict__ combb)       // (4096, 1024) bf16
{
  const int orig = blockIdx.x;        // 0..511
  const int xcd  = orig & 7;
  const int idx  = orig >> 3;         // 0..63
  const int pairIdx = idx & 15;
  const int bh   = xcd + 8 * (idx >> 4);  // 4 bh per XCD
  const int b = bh >> 4, h = bh & 15;
  const int tid = threadIdx.x;
  const int wave = tid >> 6;
  const int lane = tid & 63;
  const int l15 = lane & 15;
  const int lg  = lane >> 4;
  const int kk  = tid >> 3;           // staging k row 0..31
  const int dg  = (tid & 7) * 8;      // staging d group
  // permuted slot of k=kk, then chunk-XOR bank swizzle (thread-constant)
  const int ps_ = 2 * (kk & 15) + (kk >> 4);
  const int pcol = (((ps_ >> 3) ^ ((dg >> 3) & 3)) << 3) | (ps_ & 7);

  __shared__ short Vt[2][64][40];
  __shared__ short Gt[2][64][40];
  __shared__ short Ps[4][16][40];
  __shared__ short Pg[4][16][40];

  const bf16x8 z8 = {0, 0, 0, 0, 0, 0, 0, 0};

  for (int half = 0; half < 2; half++) {
    const int qt = half ? (31 - pairIdx) : pairIdx;
    const int q0 = qt * QB;
    const int nkt = 2 * qt + 2;       // always even
    const int qrow = wave * 16 + l15;
    const int qhi = q0 + wave * 16 + 15;

    const size_t qrb = (size_t)(b * Tc + q0 + qrow) * NALL + h * 64;
    const bf16x8 qf0 = *(const bf16x8*)&allb[qrb + lg * 8];
    const bf16x8 qf1 = *(const bf16x8*)&allb[qrb + 32 + lg * 8];
    bf16x8 rlf = z8;
    if (lg == 0) rlf = *(const bf16x8*)&RLb[(size_t)(bh * Tc + q0 + qrow) * 8];

    fx4 accS[4] = {}, accG[4] = {};
    float lpS[4] = {0.f, 0.f, 0.f, 0.f};
    float lpG[4] = {0.f, 0.f, 0.f, 0.f};

    // prologue: tile 0 into set A
    bf16x8 kA0a, kA1a, kB0a, kB1a, jw0a, jw1a, vrA, grA;
    bf16x8 kA0b, kA1b, kB0b, kB1b, jw0b, jw1b, vrB, grB;
    LOADK(0, kA0a, kA1a, kB0a, kB1a);
    LOADJW(0, jw0a, jw1a);
    LOADVG(0, vrA, grA);

    __syncthreads();   // prev half's readers done before overwriting buf0

    for (int kt = 0; kt < nkt; kt += 2) {
      const int k0a = kt * KB, k0b = k0a + KB;
      STAGEVG(0, vrA, grA);
      LOADK(k0b, kA0b, kA1b, kB0b, kB1b);
      LOADJW(k0b, jw0b, jw1b);
      LOADVG(k0b, vrB, grB);
      __syncthreads();
      COMPUTE(k0a, 0, kA0a, kA1a, kB0a, kB1a, jw0a, jw1a);
      STAGEVG(1, vrB, grB);
      if (kt + 2 < nkt) {
        LOADK(k0b + KB, kA0a, kA1a, kB0a, kB1a);
        LOADJW(k0b + KB, jw0a, jw1a);
        LOADVG(k0b + KB, vrA, grA);
      }
      __syncthreads();
      COMPUTE(k0b, 1, kA0b, kA1b, kB0b, kB1b, jw0b, jw1b);
    }

    // epilogue
    #pragma unroll
    for (int r = 0; r < 4; r++) {
      float ls = lpS[r];
      ls += __shfl_xor(ls, 1); ls += __shfl_xor(ls, 2);
      ls += __shfl_xor(ls, 4); ls += __shfl_xor(ls, 8);
      float lgeo = lpG[r];
      lgeo += __shfl_xor(lgeo, 1); lgeo += __shfl_xor(lgeo, 2);
      lgeo += __shfl_xor(lgeo, 4); lgeo += __shfl_xor(lgeo, 8);
      const int qg = q0 + wave * 16 + lg * 4 + r;
      const float gt = gate[(size_t)b * Tc + qg];
      const float invS = (1.f - gt) / ls;
      const float invG = gt / lgeo;
      #pragma unroll
      for (int dt = 0; dt < 4; dt++) {
        const float o = accS[dt][r] * invS + accG[dt][r] * invG;
        combb[(size_t)(b * Tc + qg) * 1024 + h * 64 + dt * 16 + l15] = f2bf(o);
      }
    }
  }
}

// ---------------------------------------------------------------------------
extern "C" void kernel_launch(void* const* d_in, const int* in_sizes, int n_in,
                              void* d_out, int out_size, void* d_ws, size_t ws_size,
                              hipStream_t stream) {
  (void)in_sizes; (void)n_in; (void)out_size; (void)ws_size;
  const float* x     = (const float*)d_in[0];
  const float* qkv_w = (const float*)d_in[1];
  const float* qkv_b = (const float*)d_in[2];
  const float* w1w   = (const float*)d_in[3];
  const float* w2w   = (const float*)d_in[4];
  const float* w1r   = (const float*)d_in[5];
  const float* w2r   = (const float*)d_in[6];
  const float* geow  = (const float*)d_in[7];
  const float* geob  = (const float*)d_in[8];
  const float* gatew = (const float*)d_in[9];
  const float* gateb = (const float*)d_in[10];
  const float* incs  = (const float*)d_in[11];
  const float* outw  = (const float*)d_in[12];
  const float* outb  = (const float*)d_in[13];
  float* out = (float*)d_out;

  char* p = (char*)d_ws;
  short* xb    = (short*)p;  p += (size_t)4096 * 1024 * 2;   // 8 MB
  short* wtall = (short*)p;  p += (size_t)NALL * 1024 * 2;   // 9.2 MB
  short* allb  = (short*)p;  p += (size_t)4096 * NALL * 2;   // 36.7 MB
  short* combb = (short*)p;  p += (size_t)4096 * 1024 * 2;   // 8 MB
  short* wtout = (short*)p;  p += (size_t)1024 * 1024 * 2;   // 2 MB
  short* JWb   = (short*)p;  p += (size_t)32 * 2048 * 8 * 2; // 1 MB
  short* RLb   = (short*)p;  p += (size_t)32 * 2048 * 8 * 2; // 1 MB
  float* ball  = (float*)p;  p += (size_t)NALL * 4;
  float* gatev = (float*)p;  p += (size_t)4096 * 4;

  const dim3 blk(256);

  // fused prologue: f2b | tconv_all | tconv(outw) | biasall
  prep_k<<<dim3(9618), blk, 0, stream>>>(x, qkv_w, geow, w1w, w2w, w1r, w2r,
                                         gatew, outw, qkv_b, geob, gateb,
                                         xb, wtall, wtout, ball);

  // merged projection GEMM: (4096 x 1024) @ (1024 x 4480) -> allb
  gemm_mfma_k<true><<<dim3(NALL / 128, 32), blk, 0, stream>>>(xb, wtall, ball, allb, 4096, NALL, 1024);

  lines_k<<<dim3((Bc * Tc * Hc + 255) / 256), blk, 0, stream>>>(allb, incs, JWb, RLb, gatev);

  attn3_k<<<dim3(512), blk, 0, stream>>>(allb, RLb, JWb, gatev, combb);

  // final projection -> fp32 output (64x128 tiles: 512 blocks = 2/CU)
  gemm_mfma64_k<false><<<dim3(8, 64), blk, 0, stream>>>(combb, wtout, outb, (void*)out, 4096, 1024, 1024);
}

// Round 19
// 190.724 us; speedup vs baseline: 1.3725x; 1.0009x over previous
//
#include <hip/hip_runtime.h>
#include <hip/hip_bf16.h>

#define Bc 2
#define Tc 2048
#define Dc 1024
#define Hc 16
#define Mc (Bc*Tc)   // 4096
#define QB 64
#define KB 32
#define NALL 4480    // 3072 qkv | 1024 geo | 4x64 lines | 16 gate | 112 pad

typedef __attribute__((ext_vector_type(8))) short bf16x8;
typedef __attribute__((ext_vector_type(4))) short bf16x4;
typedef __attribute__((ext_vector_type(4))) float fx4;

__device__ __forceinline__ short f2bf(float f) {
  __hip_bfloat16 h = __float2bfloat16(f);
  return *reinterpret_cast<short*>(&h);
}
__device__ __forceinline__ float bf2f(short s) {
  unsigned int u = ((unsigned int)(unsigned short)s) << 16;
  float f;
  __builtin_memcpy(&f, &u, 4);
  return f;
}
// pack two positive f32 -> (bf16(a) | bf16(b)<<16), round-half-up
__device__ __forceinline__ int pk2bf(float a, float b) {
  unsigned int ua, ub;
  __builtin_memcpy(&ua, &a, 4);
  __builtin_memcpy(&ub, &b, 4);
  return (int)(((ua + 0x8000u) >> 16) | (((ub + 0x8000u) >> 16) << 16));
}

#define MFMA(a, b, c) __builtin_amdgcn_mfma_f32_16x16x32_bf16((a), (b), (c), 0, 0, 0)

// async global->LDS, 16B per lane; LDS dest = wave-uniform base + lane*16
#define GLD16(G, L) __builtin_amdgcn_global_load_lds( \
    (const __attribute__((address_space(1))) unsigned int*)(G), \
    (__attribute__((address_space(3))) unsigned int*)(L), 16, 0, 0)

// ---------------------------------------------------------------------------
// fused prologue: blockIdx ranges ->
//   [0,4096)   : x fp32 -> bf16        [4096,8576) : merged weight T+convert
//   [8576,9600): outw T+convert        [9600,9618) : fused bias vector
// ---------------------------------------------------------------------------
__global__ __launch_bounds__(256) void prep_k(
    const float* __restrict__ x,
    const float* __restrict__ qkv_w, const float* __restrict__ geow,
    const float* __restrict__ w1w, const float* __restrict__ w2w,
    const float* __restrict__ w1r, const float* __restrict__ w2r,
    const float* __restrict__ gatew, const float* __restrict__ outw,
    const float* __restrict__ qkv_b, const float* __restrict__ geob,
    const float* __restrict__ gateb,
    short* __restrict__ xb, short* __restrict__ wtall,
    short* __restrict__ wtout, float* __restrict__ ball)
{
  __shared__ float tile[32][33];
  const int blk = blockIdx.x;

  if (blk < 4096) {                      // ---- f2b on x ----
    const int i = blk * 256 + threadIdx.x;
    const float4 v = ((const float4*)x)[i];
    bf16x4 o;
    o[0] = f2bf(v.x); o[1] = f2bf(v.y); o[2] = f2bf(v.z); o[3] = f2bf(v.w);
    ((bf16x4*)xb)[i] = o;
    return;
  }
  if (blk < 8576) {                      // ---- tconv_all ----
    const int b2 = blk - 4096;           // 0..4479 -> (n0, k0)
    const int n0 = (b2 % 140) * 32, k0 = (b2 / 140) * 32;
    const int tx = threadIdx.x & 31, ty = threadIdx.x >> 5;
    const int n = n0 + tx;
    const float* src = nullptr; int ln = 0, sN = 0;
    if (n < 3072)      { src = qkv_w; ln = n;        sN = 3072; }
    else if (n < 4096) { src = geow;  ln = n - 3072; sN = 1024; }
    else if (n < 4160) { src = w1w;   ln = n - 4096; sN = 64; }
    else if (n < 4224) { src = w2w;   ln = n - 4160; sN = 64; }
    else if (n < 4288) { src = w1r;   ln = n - 4224; sN = 64; }
    else if (n < 4352) { src = w2r;   ln = n - 4288; sN = 64; }
    else if (n < 4368) { src = gatew; ln = n - 4352; sN = 16; }
    #pragma unroll
    for (int i = 0; i < 4; i++)
      tile[ty * 4 + i][tx] = src ? src[(size_t)(k0 + ty * 4 + i) * sN + ln] : 0.f;
    __syncthreads();
    #pragma unroll
    for (int i = 0; i < 4; i++) {
      const int nn = n0 + ty * 4 + i;
      const float s = (nn < 1024) ? 0.125f : 1.f;
      wtall[(size_t)nn * 1024 + k0 + tx] = f2bf(tile[tx][ty * 4 + i] * s);
    }
    return;
  }
  if (blk < 9600) {                      // ---- tconv outw ----
    const int b3 = blk - 8576;           // 0..1023
    const int n0 = (b3 & 31) * 32, k0 = (b3 >> 5) * 32;
    const int tx = threadIdx.x & 31, ty = threadIdx.x >> 5;
    #pragma unroll
    for (int i = 0; i < 4; i++)
      tile[ty * 4 + i][tx] = outw[(size_t)(k0 + ty * 4 + i) * 1024 + n0 + tx];
    __syncthreads();
    #pragma unroll
    for (int i = 0; i < 4; i++)
      wtout[(size_t)(n0 + ty * 4 + i) * 1024 + k0 + tx] = f2bf(tile[tx][ty * 4 + i]);
    return;
  }
  {                                      // ---- biasall ----
    const int n = (blk - 9600) * 256 + threadIdx.x;
    if (n >= NALL) return;
    float v = 0.f;
    if (n < 1024)      v = qkv_b[n] * 0.125f;
    else if (n < 3072) v = qkv_b[n];
    else if (n < 4096) v = geob[n - 3072];
    else if (n >= 4352 && n < 4368) v = gateb[n - 4352];
    ball[n] = v;
  }
}

// ---------------------------------------------------------------------------
// m97-style bf16 MFMA GEMM: 128x128 tile, XCD-clustered block mapping.
// ---------------------------------------------------------------------------
template<bool BF16_OUT>
__global__ __launch_bounds__(256) void gemm_mfma_k(
    const short* __restrict__ A, const short* __restrict__ Bt,
    const float* __restrict__ bias, void* __restrict__ Cv,
    int M, int N, int K)
{
  __shared__ short As[128][32];
  __shared__ short Bs[128][32];
  // bijective XCD swizzle (nwg % 8 == 0): each XCD gets contiguous m-stripes
  const int orig = blockIdx.x + blockIdx.y * gridDim.x;
  const int q8 = (gridDim.x * gridDim.y) >> 3;
  const int idx = (orig & 7) * q8 + (orig >> 3);
  const int m0 = (idx / gridDim.x) * 128, n0 = (idx % gridDim.x) * 128;
  const int tid = threadIdx.x;
  const int wave = tid >> 6, lane = tid & 63;
  const int l15 = lane & 15, lg = lane >> 4;
  const int wm = wave >> 1, wn = wave & 1;
  const int srow = lane >> 2;
  const int schk = (lane & 3) * 8;

  const size_t aBase = (size_t)(m0 + wave * 16 + srow) * K + schk;
  const size_t bBase = (size_t)(n0 + wave * 16 + srow) * K + schk;

  fx4 acc[4][4] = {};

  for (int k0 = 0; k0 < K; k0 += 32) {
    __syncthreads();
    GLD16(&A[aBase + k0],              &As[wave * 16][0]);
    GLD16(&A[aBase + (size_t)64 * K + k0], &As[64 + wave * 16][0]);
    GLD16(&Bt[bBase + k0],             &Bs[wave * 16][0]);
    GLD16(&Bt[bBase + (size_t)64 * K + k0], &Bs[64 + wave * 16][0]);
    __syncthreads();
    bf16x8 af[4], bf[4];
    #pragma unroll
    for (int i = 0; i < 4; i++) {
      af[i] = *(const bf16x8*)&As[wm * 64 + i * 16 + l15][8 * lg];
      bf[i] = *(const bf16x8*)&Bs[wn * 64 + i * 16 + l15][8 * lg];
    }
    #pragma unroll
    for (int i = 0; i < 4; i++)
      #pragma unroll
      for (int j = 0; j < 4; j++)
        acc[i][j] = MFMA(af[i], bf[j], acc[i][j]);
  }

  #pragma unroll
  for (int i = 0; i < 4; i++)
    #pragma unroll
    for (int j = 0; j < 4; j++) {
      const int n = n0 + wn * 64 + j * 16 + l15;
      const float bv = bias ? bias[n] : 0.f;
      #pragma unroll
      for (int rg = 0; rg < 4; rg++) {
        const int m = m0 + wm * 64 + i * 16 + lg * 4 + rg;
        const float v = acc[i][j][rg] + bv;
        if constexpr (BF16_OUT)
          ((short*)Cv)[(size_t)m * N + n] = f2bf(v);
        else
          ((float*)Cv)[(size_t)m * N + n] = v;
      }
    }
}

// ---------------------------------------------------------------------------
// 64x128-tile variant for the out-GEMM (512 blocks = 2/CU), XCD-clustered.
// ---------------------------------------------------------------------------
template<bool BF16_OUT>
__global__ __launch_bounds__(256) void gemm_mfma64_k(
    const short* __restrict__ A, const short* __restrict__ Bt,
    const float* __restrict__ bias, void* __restrict__ Cv,
    int M, int N, int K)
{
  __shared__ short As[64][32];
  __shared__ short Bs[128][32];
  const int orig = blockIdx.x + blockIdx.y * gridDim.x;
  const int q8 = (gridDim.x * gridDim.y) >> 3;
  const int idx = (orig & 7) * q8 + (orig >> 3);
  const int m0 = (idx / gridDim.x) * 64, n0 = (idx % gridDim.x) * 128;
  const int tid = threadIdx.x;
  const int wave = tid >> 6, lane = tid & 63;
  const int l15 = lane & 15, lg = lane >> 4;
  const int srow = lane >> 2;
  const int schk = (lane & 3) * 8;

  const size_t aBase = (size_t)(m0 + wave * 16 + srow) * K + schk;
  const size_t bBase = (size_t)(n0 + wave * 16 + srow) * K + schk;

  fx4 acc[4][2] = {};

  for (int k0 = 0; k0 < K; k0 += 32) {
    __syncthreads();
    GLD16(&A[aBase + k0],                   &As[wave * 16][0]);
    GLD16(&Bt[bBase + k0],                  &Bs[wave * 16][0]);
    GLD16(&Bt[bBase + (size_t)64 * K + k0], &Bs[64 + wave * 16][0]);
    __syncthreads();
    bf16x8 af[4], bf[2];
    #pragma unroll
    for (int i = 0; i < 4; i++)
      af[i] = *(const bf16x8*)&As[i * 16 + l15][8 * lg];
    #pragma unroll
    for (int j = 0; j < 2; j++)
      bf[j] = *(const bf16x8*)&Bs[wave * 32 + j * 16 + l15][8 * lg];
    #pragma unroll
    for (int i = 0; i < 4; i++)
      #pragma unroll
      for (int j = 0; j < 2; j++)
        acc[i][j] = MFMA(af[i], bf[j], acc[i][j]);
  }

  #pragma unroll
  for (int i = 0; i < 4; i++)
    #pragma unroll
    for (int j = 0; j < 2; j++) {
      const int n = n0 + wave * 32 + j * 16 + l15;
      const float bv = bias ? bias[n] : 0.f;
      #pragma unroll
      for (int rg = 0; rg < 4; rg++) {
        const int m = m0 + i * 16 + lg * 4 + rg;
        const float v = acc[i][j][rg] + bv;
        if constexpr (BF16_OUT)
          ((short*)Cv)[(size_t)m * N + n] = f2bf(v);
        else
          ((float*)Cv)[(size_t)m * N + n] = v;
      }
    }
}

// ---------------------------------------------------------------------------
// Pluecker lines (+ gate fused).
// ---------------------------------------------------------------------------
__device__ __forceinline__ void exterior6(const float a[4], const float c[4], float L[6]) {
  L[0] = a[0]*c[1] - a[1]*c[0];
  L[1] = a[0]*c[2] - a[2]*c[0];
  L[2] = a[0]*c[3] - a[3]*c[0];
  L[3] = a[1]*c[2] - a[2]*c[1];
  L[4] = a[1]*c[3] - a[3]*c[1];
  L[5] = a[2]*c[3] - a[3]*c[2];
}

__device__ __forceinline__ void load4bf(const short* p, float o[4]) {
  const bf16x4 v = *(const bf16x4*)p;
  o[0] = bf2f(v[0]); o[1] = bf2f(v[1]); o[2] = bf2f(v[2]); o[3] = bf2f(v[3]);
}

__global__ void lines_k(const short* __restrict__ allb,
                        const float* __restrict__ incs,
                        short* __restrict__ JWb, short* __restrict__ RLb,
                        float* __restrict__ gatev)
{
  const int idx = blockIdx.x * 256 + threadIdx.x;
  if (idx >= Bc * Tc * Hc) return;
  const int h = idx & 15;
  const int t = (idx >> 4) & (Tc - 1);
  const int b = idx >> 15;
  const size_t row = (size_t)b * Tc + t;
  const size_t lrow = ((size_t)(b * Hc + h) * Tc + t) * 8;

  float a[4] = {0.f, 0.f, 0.f, 0.f};
  float c[4];
  load4bf(&allb[row * NALL + 4160 + h * 4], c);              // w2(x)
  if (t > 0) load4bf(&allb[(row - 1) * NALL + 4096 + h * 4], a);  // w1(x_prev)

  float L[6];
  exterior6(a, c, L);
  float n = sqrtf(L[0]*L[0] + L[1]*L[1] + L[2]*L[2] + L[3]*L[3] + L[4]*L[4] + L[5]*L[5]);
  float inv = 1.f / fmaxf(n, 1e-12f);
  const float s = incs[h];
  bf16x8 jw;
  jw[0] = f2bf( L[5] * inv * s);
  jw[1] = f2bf(-L[4] * inv * s);
  jw[2] = f2bf( L[3] * inv * s);
  jw[3] = f2bf( L[2] * inv * s);
  jw[4] = f2bf(-L[1] * inv * s);
  jw[5] = f2bf( L[0] * inv * s);
  jw[6] = 0; jw[7] = 0;
  *(bf16x8*)&JWb[lrow] = jw;

  load4bf(&allb[row * NALL + 4224 + h * 4], a);              // r1(x)
  load4bf(&allb[row * NALL + 4288 + h * 4], c);              // r2(x)
  exterior6(a, c, L);
  n = sqrtf(L[0]*L[0] + L[1]*L[1] + L[2]*L[2] + L[3]*L[3] + L[4]*L[4] + L[5]*L[5]);
  inv = 1.f / fmaxf(n, 1e-12f);
  bf16x8 rl;
  #pragma unroll
  for (int i = 0; i < 6; i++) rl[i] = f2bf(L[i] * inv);
  rl[6] = 0; rl[7] = 0;
  *(bf16x8*)&RLb[lrow] = rl;

  if (h == 0) {
    float ssum = 0.f;
    #pragma unroll
    for (int hh = 0; hh < 16; hh++) {
      const float v = bf2f(allb[row * NALL + 4352 + hh]);
      ssum += 1.f / (1.f + __expf(-v));
    }
    gatev[row] = ssum * (1.f / 16.f);
  }
}

// ---------------------------------------------------------------------------
// Dual flash attention v3 — r16 champion + MFMA row-sums: softmax denominators
// computed as P @ ones via one extra MFMA per path per tile (constant all-ones
// B-fragment: every output column = row sum). Removes the 16 VALU adds/tile
// and the epilogue shuffle chains; denominator sums the same bf16-rounded P
// as the numerator.
// ---------------------------------------------------------------------------
#define LOADK(K0, a0, a1, b0, b1) { \
  const size_t rb0 = (size_t)(b * Tc + (K0) + l15) * NALL + 1024 + h * 64; \
  const size_t rb1 = rb0 + (size_t)16 * NALL; \
  a0 = *(const bf16x8*)&allb[rb0 + lg * 8]; \
  a1 = *(const bf16x8*)&allb[rb0 + 32 + lg * 8]; \
  b0 = *(const bf16x8*)&allb[rb1 + lg * 8]; \
  b1 = *(const bf16x8*)&allb[rb1 + 32 + lg * 8]; }

#define LOADJW(K0, j0, j1) { \
  j0 = z8; j1 = z8; \
  if (lg == 0) { \
    j0 = *(const bf16x8*)&JWb[(size_t)(bh * Tc + (K0) + l15) * 8]; \
    j1 = *(const bf16x8*)&JWb[(size_t)(bh * Tc + (K0) + 16 + l15) * 8]; \
  } }

#define LOADVG(K0, vr, gr) { \
  vr = *(const bf16x8*)&allb[(size_t)(b * Tc + (K0) + kk) * NALL + 2048 + h * 64 + dg]; \
  gr = *(const bf16x8*)&allb[(size_t)(b * Tc + (K0) + kk) * NALL + 3072 + h * 64 + dg]; }

// stage row k=kk into permuted slot column (thread-constant pcol)
#define STAGEVG(CUR, vr, gr) { \
  _Pragma("unroll") for (int j = 0; j < 8; j++) { \
    const int d = dg + j; \
    Vt[CUR][d][pcol] = vr[j]; Gt[CUR][d][pcol] = gr[j]; \
  } }

#define COMPUTE(K0, CUR, ka0, ka1, kb0, kb1, jw0, jw1) \
  if ((K0) <= qhi) { \
    fx4 z = {0.f, 0.f, 0.f, 0.f}; \
    fx4 sS0, sS1, sG0, sG1; \
    __builtin_amdgcn_s_setprio(1); \
    sS0 = MFMA(qf0, ka0, z); sS0 = MFMA(qf1, ka1, sS0); \
    sS1 = MFMA(qf0, kb0, z); sS1 = MFMA(qf1, kb1, sS1); \
    sG0 = MFMA(rlf, jw0, z); sG1 = MFMA(rlf, jw1, z); \
    __builtin_amdgcn_s_setprio(0); \
    if ((K0) + KB - 1 > q0 + wave * 16) { \
      const int kg0 = (K0) + l15, kg1 = (K0) + 16 + l15; \
      _Pragma("unroll") for (int r = 0; r < 4; r++) { \
        const int qg = q0 + wave * 16 + lg * 4 + r; \
        if (kg0 > qg) { sS0[r] = -1e30f; sG0[r] = -1e30f; } \
        if (kg1 > qg) { sS1[r] = -1e30f; sG1[r] = -1e30f; } \
      } } \
    _Pragma("unroll") for (int r = 0; r < 4; r++) { \
      const int ql = lg * 4 + r; \
      *(int*)&Ps[wave][ql][2 * l15] = pk2bf(__expf(sS0[r]), __expf(sS1[r])); \
      *(int*)&Pg[wave][ql][2 * l15] = pk2bf(__expf(sG0[r]), __expf(sG1[r])); \
    } \
    const bf16x8 pa  = *(const bf16x8*)&Ps[wave][l15][8 * lg]; \
    const bf16x8 pga = *(const bf16x8*)&Pg[wave][l15][8 * lg]; \
    __builtin_amdgcn_s_setprio(1); \
    sumS = MFMA(pa, one8, sumS); \
    sumG = MFMA(pga, one8, sumG); \
    _Pragma("unroll") for (int dt = 0; dt < 4; dt++) { \
      const int dV = dt * 16 + l15; \
      const int swz = 8 * (lg ^ ((dV >> 3) & 3)); \
      accS[dt] = MFMA(pa,  *(const bf16x8*)&Vt[CUR][dV][swz], accS[dt]); \
      accG[dt] = MFMA(pga, *(const bf16x8*)&Gt[CUR][dV][swz], accG[dt]); \
    } \
    __builtin_amdgcn_s_setprio(0); \
  }

__global__ __launch_bounds__(256) void attn3_k(
    const short* __restrict__ allb,  // (4096, 4480) bf16: q|k|v|geo|lines|gate
    const short* __restrict__ RLb,   // (B*H, T, 8) bf16
    const short* __restrict__ JWb,   // (B*H, T, 8) bf16, inc_scale folded
    const float* __restrict__ gate,  // (4096)
    short* __restrict__ combb)       // (4096, 1024) bf16
{
  const int orig = blockIdx.x;        // 0..511
  const int xcd  = orig & 7;
  const int idx  = orig >> 3;         // 0..63
  const int pairIdx = idx & 15;
  const int bh   = xcd + 8 * (idx >> 4);  // 4 bh per XCD
  const int b = bh >> 4, h = bh & 15;
  const int tid = threadIdx.x;
  const int wave = tid >> 6;
  const int lane = tid & 63;
  const int l15 = lane & 15;
  const int lg  = lane >> 4;
  const int kk  = tid >> 3;           // staging k row 0..31
  const int dg  = (tid & 7) * 8;      // staging d group
  // permuted slot of k=kk, then chunk-XOR bank swizzle (thread-constant)
  const int ps_ = 2 * (kk & 15) + (kk >> 4);
  const int pcol = (((ps_ >> 3) ^ ((dg >> 3) & 3)) << 3) | (ps_ & 7);

  __shared__ short Vt[2][64][40];
  __shared__ short Gt[2][64][40];
  __shared__ short Ps[4][16][40];
  __shared__ short Pg[4][16][40];

  const bf16x8 z8 = {0, 0, 0, 0, 0, 0, 0, 0};
  const short ONE = (short)0x3F80;    // bf16 1.0
  const bf16x8 one8 = {ONE, ONE, ONE, ONE, ONE, ONE, ONE, ONE};

  for (int half = 0; half < 2; half++) {
    const int qt = half ? (31 - pairIdx) : pairIdx;
    const int q0 = qt * QB;
    const int nkt = 2 * qt + 2;       // always even
    const int qrow = wave * 16 + l15;
    const int qhi = q0 + wave * 16 + 15;

    const size_t qrb = (size_t)(b * Tc + q0 + qrow) * NALL + h * 64;
    const bf16x8 qf0 = *(const bf16x8*)&allb[qrb + lg * 8];
    const bf16x8 qf1 = *(const bf16x8*)&allb[qrb + 32 + lg * 8];
    bf16x8 rlf = z8;
    if (lg == 0) rlf = *(const bf16x8*)&RLb[(size_t)(bh * Tc + q0 + qrow) * 8];

    fx4 accS[4] = {}, accG[4] = {};
    fx4 sumS = {0.f, 0.f, 0.f, 0.f};
    fx4 sumG = {0.f, 0.f, 0.f, 0.f};

    // prologue: tile 0 into set A
    bf16x8 kA0a, kA1a, kB0a, kB1a, jw0a, jw1a, vrA, grA;
    bf16x8 kA0b, kA1b, kB0b, kB1b, jw0b, jw1b, vrB, grB;
    LOADK(0, kA0a, kA1a, kB0a, kB1a);
    LOADJW(0, jw0a, jw1a);
    LOADVG(0, vrA, grA);

    __syncthreads();   // prev half's readers done before overwriting buf0

    for (int kt = 0; kt < nkt; kt += 2) {
      const int k0a = kt * KB, k0b = k0a + KB;
      STAGEVG(0, vrA, grA);
      LOADK(k0b, kA0b, kA1b, kB0b, kB1b);
      LOADJW(k0b, jw0b, jw1b);
      LOADVG(k0b, vrB, grB);
      __syncthreads();
      COMPUTE(k0a, 0, kA0a, kA1a, kB0a, kB1a, jw0a, jw1a);
      STAGEVG(1, vrB, grB);
      if (kt + 2 < nkt) {
        LOADK(k0b + KB, kA0a, kA1a, kB0a, kB1a);
        LOADJW(k0b + KB, jw0a, jw1a);
        LOADVG(k0b + KB, vrA, grA);
      }
      __syncthreads();
      COMPUTE(k0b, 1, kA0b, kA1b, kB0b, kB1b, jw0b, jw1b);
    }

    // epilogue: sumS/sumG already hold full row sums (every output column
    // of the ones-MFMA equals the row sum) — no cross-lane reduction needed.
    #pragma unroll
    for (int r = 0; r < 4; r++) {
      const int qg = q0 + wave * 16 + lg * 4 + r;
      const float gt = gate[(size_t)b * Tc + qg];
      const float invS = (1.f - gt) / sumS[r];
      const float invG = gt / sumG[r];
      #pragma unroll
      for (int dt = 0; dt < 4; dt++) {
        const float o = accS[dt][r] * invS + accG[dt][r] * invG;
        combb[(size_t)(b * Tc + qg) * 1024 + h * 64 + dt * 16 + l15] = f2bf(o);
      }
    }
  }
}

// ---------------------------------------------------------------------------
extern "C" void kernel_launch(void* const* d_in, const int* in_sizes, int n_in,
                              void* d_out, int out_size, void* d_ws, size_t ws_size,
                              hipStream_t stream) {
  (void)in_sizes; (void)n_in; (void)out_size; (void)ws_size;
  const float* x     = (const float*)d_in[0];
  const float* qkv_w = (const float*)d_in[1];
  const float* qkv_b = (const float*)d_in[2];
  const float* w1w   = (const float*)d_in[3];
  const float* w2w   = (const float*)d_in[4];
  const float* w1r   = (const float*)d_in[5];
  const float* w2r   = (const float*)d_in[6];
  const float* geow  = (const float*)d_in[7];
  const float* geob  = (const float*)d_in[8];
  const float* gatew = (const float*)d_in[9];
  const float* gateb = (const float*)d_in[10];
  const float* incs  = (const float*)d_in[11];
  const float* outw  = (const float*)d_in[12];
  const float* outb  = (const float*)d_in[13];
  float* out = (float*)d_out;

  char* p = (char*)d_ws;
  short* xb    = (short*)p;  p += (size_t)4096 * 1024 * 2;   // 8 MB
  short* wtall = (short*)p;  p += (size_t)NALL * 1024 * 2;   // 9.2 MB
  short* allb  = (short*)p;  p += (size_t)4096 * NALL * 2;   // 36.7 MB
  short* combb = (short*)p;  p += (size_t)4096 * 1024 * 2;   // 8 MB
  short* wtout = (short*)p;  p += (size_t)1024 * 1024 * 2;   // 2 MB
  short* JWb   = (short*)p;  p += (size_t)32 * 2048 * 8 * 2; // 1 MB
  short* RLb   = (short*)p;  p += (size_t)32 * 2048 * 8 * 2; // 1 MB
  float* ball  = (float*)p;  p += (size_t)NALL * 4;
  float* gatev = (float*)p;  p += (size_t)4096 * 4;

  const dim3 blk(256);

  // fused prologue: f2b | tconv_all | tconv(outw) | biasall
  prep_k<<<dim3(9618), blk, 0, stream>>>(x, qkv_w, geow, w1w, w2w, w1r, w2r,
                                         gatew, outw, qkv_b, geob, gateb,
                                         xb, wtall, wtout, ball);

  // merged projection GEMM: (4096 x 1024) @ (1024 x 4480) -> allb
  gemm_mfma_k<true><<<dim3(NALL / 128, 32), blk, 0, stream>>>(xb, wtall, ball, allb, 4096, NALL, 1024);

  lines_k<<<dim3((Bc * Tc * Hc + 255) / 256), blk, 0, stream>>>(allb, incs, JWb, RLb, gatev);

  attn3_k<<<dim3(512), blk, 0, stream>>>(allb, RLb, JWb, gatev, combb);

  // final projection -> fp32 output (64x128 tiles: 512 blocks = 2/CU)
  gemm_mfma64_k<false><<<dim3(8, 64), blk, 0, stream>>>(combb, wtout, outb, (void*)out, 4096, 1024, 1024);
}

// Round 20
// 189.854 us; speedup vs baseline: 1.3788x; 1.0046x over previous
//
#include <hip/hip_runtime.h>
#include <hip/hip_bf16.h>

#define Bc 2
#define Tc 2048
#define Dc 1024
#define Hc 16
#define Mc (Bc*Tc)   // 4096
#define QB 64
#define KB 32
#define NALL 4480    // 3072 qkv | 1024 geo | 4x64 lines | 16 gate | 112 pad

typedef __attribute__((ext_vector_type(8))) short bf16x8;
typedef __attribute__((ext_vector_type(4))) short bf16x4;
typedef __attribute__((ext_vector_type(4))) float fx4;

__device__ __forceinline__ short f2bf(float f) {
  __hip_bfloat16 h = __float2bfloat16(f);
  return *reinterpret_cast<short*>(&h);
}
__device__ __forceinline__ float bf2f(short s) {
  unsigned int u = ((unsigned int)(unsigned short)s) << 16;
  float f;
  __builtin_memcpy(&f, &u, 4);
  return f;
}
// pack two positive f32 -> (bf16(a) | bf16(b)<<16), round-half-up
__device__ __forceinline__ int pk2bf(float a, float b) {
  unsigned int ua, ub;
  __builtin_memcpy(&ua, &a, 4);
  __builtin_memcpy(&ub, &b, 4);
  return (int)(((ua + 0x8000u) >> 16) | (((ub + 0x8000u) >> 16) << 16));
}

#define MFMA(a, b, c) __builtin_amdgcn_mfma_f32_16x16x32_bf16((a), (b), (c), 0, 0, 0)

// async global->LDS, 16B per lane; LDS dest = wave-uniform base + lane*16
#define GLD16(G, L) __builtin_amdgcn_global_load_lds( \
    (const __attribute__((address_space(1))) unsigned int*)(G), \
    (__attribute__((address_space(3))) unsigned int*)(L), 16, 0, 0)

// ---------------------------------------------------------------------------
// fused prologue: blockIdx ranges ->
//   [0,4096)   : x fp32 -> bf16        [4096,8576) : merged weight T+convert
//   [8576,9600): outw T+convert        [9600,9618) : fused bias vector
// ---------------------------------------------------------------------------
__global__ __launch_bounds__(256) void prep_k(
    const float* __restrict__ x,
    const float* __restrict__ qkv_w, const float* __restrict__ geow,
    const float* __restrict__ w1w, const float* __restrict__ w2w,
    const float* __restrict__ w1r, const float* __restrict__ w2r,
    const float* __restrict__ gatew, const float* __restrict__ outw,
    const float* __restrict__ qkv_b, const float* __restrict__ geob,
    const float* __restrict__ gateb,
    short* __restrict__ xb, short* __restrict__ wtall,
    short* __restrict__ wtout, float* __restrict__ ball)
{
  __shared__ float tile[32][33];
  const int blk = blockIdx.x;

  if (blk < 4096) {                      // ---- f2b on x ----
    const int i = blk * 256 + threadIdx.x;
    const float4 v = ((const float4*)x)[i];
    bf16x4 o;
    o[0] = f2bf(v.x); o[1] = f2bf(v.y); o[2] = f2bf(v.z); o[3] = f2bf(v.w);
    ((bf16x4*)xb)[i] = o;
    return;
  }
  if (blk < 8576) {                      // ---- tconv_all ----
    const int b2 = blk - 4096;           // 0..4479 -> (n0, k0)
    const int n0 = (b2 % 140) * 32, k0 = (b2 / 140) * 32;
    const int tx = threadIdx.x & 31, ty = threadIdx.x >> 5;
    const int n = n0 + tx;
    const float* src = nullptr; int ln = 0, sN = 0;
    if (n < 3072)      { src = qkv_w; ln = n;        sN = 3072; }
    else if (n < 4096) { src = geow;  ln = n - 3072; sN = 1024; }
    else if (n < 4160) { src = w1w;   ln = n - 4096; sN = 64; }
    else if (n < 4224) { src = w2w;   ln = n - 4160; sN = 64; }
    else if (n < 4288) { src = w1r;   ln = n - 4224; sN = 64; }
    else if (n < 4352) { src = w2r;   ln = n - 4288; sN = 64; }
    else if (n < 4368) { src = gatew; ln = n - 4352; sN = 16; }
    #pragma unroll
    for (int i = 0; i < 4; i++)
      tile[ty * 4 + i][tx] = src ? src[(size_t)(k0 + ty * 4 + i) * sN + ln] : 0.f;
    __syncthreads();
    #pragma unroll
    for (int i = 0; i < 4; i++) {
      const int nn = n0 + ty * 4 + i;
      const float s = (nn < 1024) ? 0.125f : 1.f;
      wtall[(size_t)nn * 1024 + k0 + tx] = f2bf(tile[tx][ty * 4 + i] * s);
    }
    return;
  }
  if (blk < 9600) {                      // ---- tconv outw ----
    const int b3 = blk - 8576;           // 0..1023
    const int n0 = (b3 & 31) * 32, k0 = (b3 >> 5) * 32;
    const int tx = threadIdx.x & 31, ty = threadIdx.x >> 5;
    #pragma unroll
    for (int i = 0; i < 4; i++)
      tile[ty * 4 + i][tx] = outw[(size_t)(k0 + ty * 4 + i) * 1024 + n0 + tx];
    __syncthreads();
    #pragma unroll
    for (int i = 0; i < 4; i++)
      wtout[(size_t)(n0 + ty * 4 + i) * 1024 + k0 + tx] = f2bf(tile[tx][ty * 4 + i]);
    return;
  }
  {                                      // ---- biasall ----
    const int n = (blk - 9600) * 256 + threadIdx.x;
    if (n >= NALL) return;
    float v = 0.f;
    if (n < 1024)      v = qkv_b[n] * 0.125f;
    else if (n < 3072) v = qkv_b[n];
    else if (n < 4096) v = geob[n - 3072];
    else if (n >= 4352 && n < 4368) v = gateb[n - 4352];
    ball[n] = v;
  }
}

// ---------------------------------------------------------------------------
// m97-style bf16 MFMA GEMM, 128x128 tile, XCD-clustered — now with
// double-buffered LDS and ONE barrier per K-step (T3 "minimum 2-phase"):
// stage tile t+1 into buf^1 before computing tile t; the single end-of-iter
// barrier both drains the in-flight global_load_lds and releases the buffer.
// ---------------------------------------------------------------------------
template<bool BF16_OUT>
__global__ __launch_bounds__(256) void gemm_mfma_k(
    const short* __restrict__ A, const short* __restrict__ Bt,
    const float* __restrict__ bias, void* __restrict__ Cv,
    int M, int N, int K)
{
  __shared__ short As[2][128][32];
  __shared__ short Bs[2][128][32];
  // bijective XCD swizzle (nwg % 8 == 0): each XCD gets contiguous m-stripes
  const int orig = blockIdx.x + blockIdx.y * gridDim.x;
  const int q8 = (gridDim.x * gridDim.y) >> 3;
  const int idx = (orig & 7) * q8 + (orig >> 3);
  const int m0 = (idx / gridDim.x) * 128, n0 = (idx % gridDim.x) * 128;
  const int tid = threadIdx.x;
  const int wave = tid >> 6, lane = tid & 63;
  const int l15 = lane & 15, lg = lane >> 4;
  const int wm = wave >> 1, wn = wave & 1;
  const int srow = lane >> 2;
  const int schk = (lane & 3) * 8;

  const size_t aBase = (size_t)(m0 + wave * 16 + srow) * K + schk;
  const size_t bBase = (size_t)(n0 + wave * 16 + srow) * K + schk;

  fx4 acc[4][4] = {};

#define GSTAGE_G(BUF, KO) { \
    GLD16(&A[aBase + (KO)],                 &As[BUF][wave * 16][0]); \
    GLD16(&A[aBase + (size_t)64 * K + (KO)], &As[BUF][64 + wave * 16][0]); \
    GLD16(&Bt[bBase + (KO)],                &Bs[BUF][wave * 16][0]); \
    GLD16(&Bt[bBase + (size_t)64 * K + (KO)], &Bs[BUF][64 + wave * 16][0]); }

  GSTAGE_G(0, 0);
  __syncthreads();            // buf0 ready (barrier drains vmcnt)

  int cur = 0;
  for (int k0 = 0; k0 < K; k0 += 32) {
    if (k0 + 32 < K) GSTAGE_G(cur ^ 1, k0 + 32);
    bf16x8 af[4], bf[4];
    #pragma unroll
    for (int i = 0; i < 4; i++) {
      af[i] = *(const bf16x8*)&As[cur][wm * 64 + i * 16 + l15][8 * lg];
      bf[i] = *(const bf16x8*)&Bs[cur][wn * 64 + i * 16 + l15][8 * lg];
    }
    #pragma unroll
    for (int i = 0; i < 4; i++)
      #pragma unroll
      for (int j = 0; j < 4; j++)
        acc[i][j] = MFMA(af[i], bf[j], acc[i][j]);
    __syncthreads();          // next buf ready; readers of cur done
    cur ^= 1;
  }
#undef GSTAGE_G

  #pragma unroll
  for (int i = 0; i < 4; i++)
    #pragma unroll
    for (int j = 0; j < 4; j++) {
      const int n = n0 + wn * 64 + j * 16 + l15;
      const float bv = bias ? bias[n] : 0.f;
      #pragma unroll
      for (int rg = 0; rg < 4; rg++) {
        const int m = m0 + wm * 64 + i * 16 + lg * 4 + rg;
        const float v = acc[i][j][rg] + bv;
        if constexpr (BF16_OUT)
          ((short*)Cv)[(size_t)m * N + n] = f2bf(v);
        else
          ((float*)Cv)[(size_t)m * N + n] = v;
      }
    }
}

// ---------------------------------------------------------------------------
// 64x128-tile variant for the out-GEMM (512 blocks = 2/CU), XCD-clustered.
// (kept as r16 control: 2 barriers per K-step)
// ---------------------------------------------------------------------------
template<bool BF16_OUT>
__global__ __launch_bounds__(256) void gemm_mfma64_k(
    const short* __restrict__ A, const short* __restrict__ Bt,
    const float* __restrict__ bias, void* __restrict__ Cv,
    int M, int N, int K)
{
  __shared__ short As[64][32];
  __shared__ short Bs[128][32];
  const int orig = blockIdx.x + blockIdx.y * gridDim.x;
  const int q8 = (gridDim.x * gridDim.y) >> 3;
  const int idx = (orig & 7) * q8 + (orig >> 3);
  const int m0 = (idx / gridDim.x) * 64, n0 = (idx % gridDim.x) * 128;
  const int tid = threadIdx.x;
  const int wave = tid >> 6, lane = tid & 63;
  const int l15 = lane & 15, lg = lane >> 4;
  const int srow = lane >> 2;
  const int schk = (lane & 3) * 8;

  const size_t aBase = (size_t)(m0 + wave * 16 + srow) * K + schk;
  const size_t bBase = (size_t)(n0 + wave * 16 + srow) * K + schk;

  fx4 acc[4][2] = {};

  for (int k0 = 0; k0 < K; k0 += 32) {
    __syncthreads();
    GLD16(&A[aBase + k0],                   &As[wave * 16][0]);
    GLD16(&Bt[bBase + k0],                  &Bs[wave * 16][0]);
    GLD16(&Bt[bBase + (size_t)64 * K + k0], &Bs[64 + wave * 16][0]);
    __syncthreads();
    bf16x8 af[4], bf[2];
    #pragma unroll
    for (int i = 0; i < 4; i++)
      af[i] = *(const bf16x8*)&As[i * 16 + l15][8 * lg];
    #pragma unroll
    for (int j = 0; j < 2; j++)
      bf[j] = *(const bf16x8*)&Bs[wave * 32 + j * 16 + l15][8 * lg];
    #pragma unroll
    for (int i = 0; i < 4; i++)
      #pragma unroll
      for (int j = 0; j < 2; j++)
        acc[i][j] = MFMA(af[i], bf[j], acc[i][j]);
  }

  #pragma unroll
  for (int i = 0; i < 4; i++)
    #pragma unroll
    for (int j = 0; j < 2; j++) {
      const int n = n0 + wave * 32 + j * 16 + l15;
      const float bv = bias ? bias[n] : 0.f;
      #pragma unroll
      for (int rg = 0; rg < 4; rg++) {
        const int m = m0 + i * 16 + lg * 4 + rg;
        const float v = acc[i][j][rg] + bv;
        if constexpr (BF16_OUT)
          ((short*)Cv)[(size_t)m * N + n] = f2bf(v);
        else
          ((float*)Cv)[(size_t)m * N + n] = v;
      }
    }
}

// ---------------------------------------------------------------------------
// Pluecker lines (+ gate fused).
// ---------------------------------------------------------------------------
__device__ __forceinline__ void exterior6(const float a[4], const float c[4], float L[6]) {
  L[0] = a[0]*c[1] - a[1]*c[0];
  L[1] = a[0]*c[2] - a[2]*c[0];
  L[2] = a[0]*c[3] - a[3]*c[0];
  L[3] = a[1]*c[2] - a[2]*c[1];
  L[4] = a[1]*c[3] - a[3]*c[1];
  L[5] = a[2]*c[3] - a[3]*c[2];
}

__device__ __forceinline__ void load4bf(const short* p, float o[4]) {
  const bf16x4 v = *(const bf16x4*)p;
  o[0] = bf2f(v[0]); o[1] = bf2f(v[1]); o[2] = bf2f(v[2]); o[3] = bf2f(v[3]);
}

__global__ void lines_k(const short* __restrict__ allb,
                        const float* __restrict__ incs,
                        short* __restrict__ JWb, short* __restrict__ RLb,
                        float* __restrict__ gatev)
{
  const int idx = blockIdx.x * 256 + threadIdx.x;
  if (idx >= Bc * Tc * Hc) return;
  const int h = idx & 15;
  const int t = (idx >> 4) & (Tc - 1);
  const int b = idx >> 15;
  const size_t row = (size_t)b * Tc + t;
  const size_t lrow = ((size_t)(b * Hc + h) * Tc + t) * 8;

  float a[4] = {0.f, 0.f, 0.f, 0.f};
  float c[4];
  load4bf(&allb[row * NALL + 4160 + h * 4], c);              // w2(x)
  if (t > 0) load4bf(&allb[(row - 1) * NALL + 4096 + h * 4], a);  // w1(x_prev)

  float L[6];
  exterior6(a, c, L);
  float n = sqrtf(L[0]*L[0] + L[1]*L[1] + L[2]*L[2] + L[3]*L[3] + L[4]*L[4] + L[5]*L[5]);
  float inv = 1.f / fmaxf(n, 1e-12f);
  const float s = incs[h];
  bf16x8 jw;
  jw[0] = f2bf( L[5] * inv * s);
  jw[1] = f2bf(-L[4] * inv * s);
  jw[2] = f2bf( L[3] * inv * s);
  jw[3] = f2bf( L[2] * inv * s);
  jw[4] = f2bf(-L[1] * inv * s);
  jw[5] = f2bf( L[0] * inv * s);
  jw[6] = 0; jw[7] = 0;
  *(bf16x8*)&JWb[lrow] = jw;

  load4bf(&allb[row * NALL + 4224 + h * 4], a);              // r1(x)
  load4bf(&allb[row * NALL + 4288 + h * 4], c);              // r2(x)
  exterior6(a, c, L);
  n = sqrtf(L[0]*L[0] + L[1]*L[1] + L[2]*L[2] + L[3]*L[3] + L[4]*L[4] + L[5]*L[5]);
  inv = 1.f / fmaxf(n, 1e-12f);
  bf16x8 rl;
  #pragma unroll
  for (int i = 0; i < 6; i++) rl[i] = f2bf(L[i] * inv);
  rl[6] = 0; rl[7] = 0;
  *(bf16x8*)&RLb[lrow] = rl;

  if (h == 0) {
    float ssum = 0.f;
    #pragma unroll
    for (int hh = 0; hh < 16; hh++) {
      const float v = bf2f(allb[row * NALL + 4352 + hh]);
      ssum += 1.f / (1.f + __expf(-v));
    }
    gatev[row] = ssum * (1.f / 16.f);
  }
}

// ---------------------------------------------------------------------------
// Dual flash attention v3 — r19 champion: paired q-tiles, XCD clustering,
// double-buffered V/G staging, pair-packed P stores, MFMA row-sums.
// ---------------------------------------------------------------------------
#define LOADK(K0, a0, a1, b0, b1) { \
  const size_t rb0 = (size_t)(b * Tc + (K0) + l15) * NALL + 1024 + h * 64; \
  const size_t rb1 = rb0 + (size_t)16 * NALL; \
  a0 = *(const bf16x8*)&allb[rb0 + lg * 8]; \
  a1 = *(const bf16x8*)&allb[rb0 + 32 + lg * 8]; \
  b0 = *(const bf16x8*)&allb[rb1 + lg * 8]; \
  b1 = *(const bf16x8*)&allb[rb1 + 32 + lg * 8]; }

#define LOADJW(K0, j0, j1) { \
  j0 = z8; j1 = z8; \
  if (lg == 0) { \
    j0 = *(const bf16x8*)&JWb[(size_t)(bh * Tc + (K0) + l15) * 8]; \
    j1 = *(const bf16x8*)&JWb[(size_t)(bh * Tc + (K0) + 16 + l15) * 8]; \
  } }

#define LOADVG(K0, vr, gr) { \
  vr = *(const bf16x8*)&allb[(size_t)(b * Tc + (K0) + kk) * NALL + 2048 + h * 64 + dg]; \
  gr = *(const bf16x8*)&allb[(size_t)(b * Tc + (K0) + kk) * NALL + 3072 + h * 64 + dg]; }

// stage row k=kk into permuted slot column (thread-constant pcol)
#define STAGEVG(CUR, vr, gr) { \
  _Pragma("unroll") for (int j = 0; j < 8; j++) { \
    const int d = dg + j; \
    Vt[CUR][d][pcol] = vr[j]; Gt[CUR][d][pcol] = gr[j]; \
  } }

#define COMPUTE(K0, CUR, ka0, ka1, kb0, kb1, jw0, jw1) \
  if ((K0) <= qhi) { \
    fx4 z = {0.f, 0.f, 0.f, 0.f}; \
    fx4 sS0, sS1, sG0, sG1; \
    __builtin_amdgcn_s_setprio(1); \
    sS0 = MFMA(qf0, ka0, z); sS0 = MFMA(qf1, ka1, sS0); \
    sS1 = MFMA(qf0, kb0, z); sS1 = MFMA(qf1, kb1, sS1); \
    sG0 = MFMA(rlf, jw0, z); sG1 = MFMA(rlf, jw1, z); \
    __builtin_amdgcn_s_setprio(0); \
    if ((K0) + KB - 1 > q0 + wave * 16) { \
      const int kg0 = (K0) + l15, kg1 = (K0) + 16 + l15; \
      _Pragma("unroll") for (int r = 0; r < 4; r++) { \
        const int qg = q0 + wave * 16 + lg * 4 + r; \
        if (kg0 > qg) { sS0[r] = -1e30f; sG0[r] = -1e30f; } \
        if (kg1 > qg) { sS1[r] = -1e30f; sG1[r] = -1e30f; } \
      } } \
    _Pragma("unroll") for (int r = 0; r < 4; r++) { \
      const int ql = lg * 4 + r; \
      *(int*)&Ps[wave][ql][2 * l15] = pk2bf(__expf(sS0[r]), __expf(sS1[r])); \
      *(int*)&Pg[wave][ql][2 * l15] = pk2bf(__expf(sG0[r]), __expf(sG1[r])); \
    } \
    const bf16x8 pa  = *(const bf16x8*)&Ps[wave][l15][8 * lg]; \
    const bf16x8 pga = *(const bf16x8*)&Pg[wave][l15][8 * lg]; \
    __builtin_amdgcn_s_setprio(1); \
    sumS = MFMA(pa, one8, sumS); \
    sumG = MFMA(pga, one8, sumG); \
    _Pragma("unroll") for (int dt = 0; dt < 4; dt++) { \
      const int dV = dt * 16 + l15; \
      const int swz = 8 * (lg ^ ((dV >> 3) & 3)); \
      accS[dt] = MFMA(pa,  *(const bf16x8*)&Vt[CUR][dV][swz], accS[dt]); \
      accG[dt] = MFMA(pga, *(const bf16x8*)&Gt[CUR][dV][swz], accG[dt]); \
    } \
    __builtin_amdgcn_s_setprio(0); \
  }

__global__ __launch_bounds__(256) void attn3_k(
    const short* __restrict__ allb,  // (4096, 4480) bf16: q|k|v|geo|lines|gate
    const short* __restrict__ RLb,   // (B*H, T, 8) bf16
    const short* __restrict__ JWb,   // (B*H, T, 8) bf16, inc_scale folded
    const float* __restrict__ gate,  // (4096)
    short* __restrict__ combb)       // (4096, 1024) bf16
{
  const int orig = blockIdx.x;        // 0..511
  const int xcd  = orig & 7;
  const int idx  = orig >> 3;         // 0..63
  const int pairIdx = idx & 15;
  const int bh   = xcd + 8 * (idx >> 4);  // 4 bh per XCD
  const int b = bh >> 4, h = bh & 15;
  const int tid = threadIdx.x;
  const int wave = tid >> 6;
  const int lane = tid & 63;
  const int l15 = lane & 15;
  const int lg  = lane >> 4;
  const int kk  = tid >> 3;           // staging k row 0..31
  const int dg  = (tid & 7) * 8;      // staging d group
  // permuted slot of k=kk, then chunk-XOR bank swizzle (thread-constant)
  const int ps_ = 2 * (kk & 15) + (kk >> 4);
  const int pcol = (((ps_ >> 3) ^ ((dg >> 3) & 3)) << 3) | (ps_ & 7);

  __shared__ short Vt[2][64][40];
  __shared__ short Gt[2][64][40];
  __shared__ short Ps[4][16][40];
  __shared__ short Pg[4][16][40];

  const bf16x8 z8 = {0, 0, 0, 0, 0, 0, 0, 0};
  const short ONE = (short)0x3F80;    // bf16 1.0
  const bf16x8 one8 = {ONE, ONE, ONE, ONE, ONE, ONE, ONE, ONE};

  for (int half = 0; half < 2; half++) {
    const int qt = half ? (31 - pairIdx) : pairIdx;
    const int q0 = qt * QB;
    const int nkt = 2 * qt + 2;       // always even
    const int qrow = wave * 16 + l15;
    const int qhi = q0 + wave * 16 + 15;

    const size_t qrb = (size_t)(b * Tc + q0 + qrow) * NALL + h * 64;
    const bf16x8 qf0 = *(const bf16x8*)&allb[qrb + lg * 8];
    const bf16x8 qf1 = *(const bf16x8*)&allb[qrb + 32 + lg * 8];
    bf16x8 rlf = z8;
    if (lg == 0) rlf = *(const bf16x8*)&RLb[(size_t)(bh * Tc + q0 + qrow) * 8];

    fx4 accS[4] = {}, accG[4] = {};
    fx4 sumS = {0.f, 0.f, 0.f, 0.f};
    fx4 sumG = {0.f, 0.f, 0.f, 0.f};

    // prologue: tile 0 into set A
    bf16x8 kA0a, kA1a, kB0a, kB1a, jw0a, jw1a, vrA, grA;
    bf16x8 kA0b, kA1b, kB0b, kB1b, jw0b, jw1b, vrB, grB;
    LOADK(0, kA0a, kA1a, kB0a, kB1a);
    LOADJW(0, jw0a, jw1a);
    LOADVG(0, vrA, grA);

    __syncthreads();   // prev half's readers done before overwriting buf0

    for (int kt = 0; kt < nkt; kt += 2) {
      const int k0a = kt * KB, k0b = k0a + KB;
      STAGEVG(0, vrA, grA);
      LOADK(k0b, kA0b, kA1b, kB0b, kB1b);
      LOADJW(k0b, jw0b, jw1b);
      LOADVG(k0b, vrB, grB);
      __syncthreads();
      COMPUTE(k0a, 0, kA0a, kA1a, kB0a, kB1a, jw0a, jw1a);
      STAGEVG(1, vrB, grB);
      if (kt + 2 < nkt) {
        LOADK(k0b + KB, kA0a, kA1a, kB0a, kB1a);
        LOADJW(k0b + KB, jw0a, jw1a);
        LOADVG(k0b + KB, vrA, grA);
      }
      __syncthreads();
      COMPUTE(k0b, 1, kA0b, kA1b, kB0b, kB1b, jw0b, jw1b);
    }

    // epilogue: sumS/sumG already hold full row sums
    #pragma unroll
    for (int r = 0; r < 4; r++) {
      const int qg = q0 + wave * 16 + lg * 4 + r;
      const float gt = gate[(size_t)b * Tc + qg];
      const float invS = (1.f - gt) / sumS[r];
      const float invG = gt / sumG[r];
      #pragma unroll
      for (int dt = 0; dt < 4; dt++) {
        const float o = accS[dt][r] * invS + accG[dt][r] * invG;
        combb[(size_t)(b * Tc + qg) * 1024 + h * 64 + dt * 16 + l15] = f2bf(o);
      }
    }
  }
}

// ---------------------------------------------------------------------------
extern "C" void kernel_launch(void* const* d_in, const int* in_sizes, int n_in,
                              void* d_out, int out_size, void* d_ws, size_t ws_size,
                              hipStream_t stream) {
  (void)in_sizes; (void)n_in; (void)out_size; (void)ws_size;
  const float* x     = (const float*)d_in[0];
  const float* qkv_w = (const float*)d_in[1];
  const float* qkv_b = (const float*)d_in[2];
  const float* w1w   = (const float*)d_in[3];
  const float* w2w   = (const float*)d_in[4];
  const float* w1r   = (const float*)d_in[5];
  const float* w2r   = (const float*)d_in[6];
  const float* geow  = (const float*)d_in[7];
  const float* geob  = (const float*)d_in[8];
  const float* gatew = (const float*)d_in[9];
  const float* gateb = (const float*)d_in[10];
  const float* incs  = (const float*)d_in[11];
  const float* outw  = (const float*)d_in[12];
  const float* outb  = (const float*)d_in[13];
  float* out = (float*)d_out;

  char* p = (char*)d_ws;
  short* xb    = (short*)p;  p += (size_t)4096 * 1024 * 2;   // 8 MB
  short* wtall = (short*)p;  p += (size_t)NALL * 1024 * 2;   // 9.2 MB
  short* allb  = (short*)p;  p += (size_t)4096 * NALL * 2;   // 36.7 MB
  short* combb = (short*)p;  p += (size_t)4096 * 1024 * 2;   // 8 MB
  short* wtout = (short*)p;  p += (size_t)1024 * 1024 * 2;   // 2 MB
  short* JWb   = (short*)p;  p += (size_t)32 * 2048 * 8 * 2; // 1 MB
  short* RLb   = (short*)p;  p += (size_t)32 * 2048 * 8 * 2; // 1 MB
  float* ball  = (float*)p;  p += (size_t)NALL * 4;
  float* gatev = (float*)p;  p += (size_t)4096 * 4;

  const dim3 blk(256);

  // fused prologue: f2b | tconv_all | tconv(outw) | biasall
  prep_k<<<dim3(9618), blk, 0, stream>>>(x, qkv_w, geow, w1w, w2w, w1r, w2r,
                                         gatew, outw, qkv_b, geob, gateb,
                                         xb, wtall, wtout, ball);

  // merged projection GEMM: (4096 x 1024) @ (1024 x 4480) -> allb
  gemm_mfma_k<true><<<dim3(NALL / 128, 32), blk, 0, stream>>>(xb, wtall, ball, allb, 4096, NALL, 1024);

  lines_k<<<dim3((Bc * Tc * Hc + 255) / 256), blk, 0, stream>>>(allb, incs, JWb, RLb, gatev);

  attn3_k<<<dim3(512), blk, 0, stream>>>(allb, RLb, JWb, gatev, combb);

  // final projection -> fp32 output (64x128 tiles: 512 blocks = 2/CU)
  gemm_mfma64_k<false><<<dim3(8, 64), blk, 0, stream>>>(combb, wtout, outb, (void*)out, 4096, 1024, 1024);
}